// Round 1
// baseline (5532.157 us; speedup 1.0000x reference)
//
#include <hip/hip_runtime.h>

#define N_NODES 50000
#define N_EDGES 500000
#define NUM_G   128

__global__ void deg_kernel(const int* __restrict__ src, const float* __restrict__ ea,
                           float* __restrict__ deg, int E) {
    int e = blockIdx.x * blockDim.x + threadIdx.x;
    if (e < E) atomicAdd(&deg[src[e]], ea[e]);
}

__global__ void dinv_kernel(const float* __restrict__ deg, float* __restrict__ dinv, int n) {
    int i = blockIdx.x * blockDim.x + threadIdx.x;
    if (i >= n) return;
    float d = deg[i];
    float r = 0.0f;
    if (d > 0.0f) {
        r = rsqrtf(d);
        r = r * (1.5f - 0.5f * d * r * r);   // Newton refine to ~fp32 exact
    }
    dinv[i] = r;
}

__global__ void edgew_kernel(const int* __restrict__ src, const int* __restrict__ dst,
                             const float* __restrict__ ea, const float* __restrict__ dinv,
                             float* __restrict__ w, int E) {
    int e = blockIdx.x * blockDim.x + threadIdx.x;
    if (e < E) w[e] = -dinv[src[e]] * ea[e] * dinv[dst[e]];
}

// out[dst[e]][:] += w[e] * X[src[e]][:]   (atomic scatter, float4 per thread)
__global__ void propagate_kernel(const float* __restrict__ X, const int* __restrict__ src,
                                 const int* __restrict__ dst, const float* __restrict__ w,
                                 float* __restrict__ out, int E, int Fq) {
    long long t = (long long)blockIdx.x * blockDim.x + threadIdx.x;
    int e = (int)(t / Fq);
    if (e >= E) return;
    int f4 = (int)(t % Fq);
    float we = w[e];
    int s = src[e], d = dst[e];
    const float4 xv = *reinterpret_cast<const float4*>(X + (size_t)s * (Fq * 4) + f4 * 4);
    float* o = out + (size_t)d * (Fq * 4) + f4 * 4;
    atomicAdd(o + 0, we * xv.x);
    atomicAdd(o + 1, we * xv.y);
    atomicAdd(o + 2, we * xv.z);
    atomicAdd(o + 3, we * xv.w);
}

// C[n][j..j+3] (+)= sum_k A[n][k] * W[k][j..j+3]
__global__ void matmul_kernel(const float* __restrict__ A, const float* __restrict__ W,
                              float* __restrict__ C, int nrows, int Fin, int Fout, int acc_flag) {
    int jq = Fout >> 2;
    long long t = (long long)blockIdx.x * blockDim.x + threadIdx.x;
    int n = (int)(t / jq);
    if (n >= nrows) return;
    int j = (int)(t % jq) * 4;
    const float* a = A + (size_t)n * Fin;
    float4 acc;
    if (acc_flag) acc = *reinterpret_cast<const float4*>(C + (size_t)n * Fout + j);
    else          acc = make_float4(0.f, 0.f, 0.f, 0.f);
    for (int k = 0; k < Fin; k += 4) {
        float4 av = *reinterpret_cast<const float4*>(a + k);
        float4 w0 = *reinterpret_cast<const float4*>(W + (size_t)(k + 0) * Fout + j);
        float4 w1 = *reinterpret_cast<const float4*>(W + (size_t)(k + 1) * Fout + j);
        float4 w2 = *reinterpret_cast<const float4*>(W + (size_t)(k + 2) * Fout + j);
        float4 w3 = *reinterpret_cast<const float4*>(W + (size_t)(k + 3) * Fout + j);
        acc.x += av.x * w0.x + av.y * w1.x + av.z * w2.x + av.w * w3.x;
        acc.y += av.x * w0.y + av.y * w1.y + av.z * w2.y + av.w * w3.y;
        acc.z += av.x * w0.z + av.y * w1.z + av.z * w2.z + av.w * w3.z;
        acc.w += av.x * w0.w + av.y * w1.w + av.z * w2.w + av.w * w3.w;
    }
    *reinterpret_cast<float4*>(C + (size_t)n * Fout + j) = acc;
}

// T2 = 2*T2 - T0 elementwise (float4)
__global__ void combine_kernel(float* __restrict__ T2, const float* __restrict__ T0, long long n4) {
    long long t = (long long)blockIdx.x * blockDim.x + threadIdx.x;
    if (t >= n4) return;
    float4 p = reinterpret_cast<float4*>(T2)[t];
    float4 x0 = reinterpret_cast<const float4*>(T0)[t];
    p.x = 2.0f * p.x - x0.x;
    p.y = 2.0f * p.y - x0.y;
    p.z = 2.0f * p.z - x0.z;
    p.w = 2.0f * p.w - x0.w;
    reinterpret_cast<float4*>(T2)[t] = p;
}

__global__ void bias_relu_kernel(float* __restrict__ C, const float* __restrict__ b,
                                 int nrows, int Fout) {
    int jq = Fout >> 2;
    long long t = (long long)blockIdx.x * blockDim.x + threadIdx.x;
    int n = (int)(t / jq);
    if (n >= nrows) return;
    int j = (int)(t % jq) * 4;
    float4 v = *reinterpret_cast<float4*>(C + (size_t)n * Fout + j);
    float4 bv = *reinterpret_cast<const float4*>(b + j);
    v.x = fmaxf(v.x + bv.x, 0.f);
    v.y = fmaxf(v.y + bv.y, 0.f);
    v.z = fmaxf(v.z + bv.z, 0.f);
    v.w = fmaxf(v.w + bv.w, 0.f);
    *reinterpret_cast<float4*>(C + (size_t)n * Fout + j) = v;
}

__device__ __forceinline__ int lower_bound_dev(const int* __restrict__ a, int n, int v) {
    int lo = 0, hi = n;
    while (lo < hi) {
        int mid = (lo + hi) >> 1;
        if (a[mid] < v) lo = mid + 1; else hi = mid;
    }
    return lo;
}

// One block per graph: mean-pool H (N x 32) over node range, then 32->2 linear.
__global__ void pool_kernel(const float* __restrict__ H, const int* __restrict__ batch,
                            const float* __restrict__ Wl, const float* __restrict__ bl,
                            float* __restrict__ out, int n) {
    int g = blockIdx.x;
    int start = lower_bound_dev(batch, n, g);
    int end   = lower_bound_dev(batch, n, g + 1);
    int tid = threadIdx.x;
    int f = tid & 31;
    int sub = tid >> 5;  // 0..7
    float acc = 0.0f;
    for (int i = start + sub; i < end; i += 8)
        acc += H[(size_t)i * 32 + f];
    __shared__ float red[256];
    red[tid] = acc;
    __syncthreads();
    if (tid < 128) red[tid] += red[tid + 128];
    __syncthreads();
    if (tid < 64) red[tid] += red[tid + 64];
    __syncthreads();
    if (tid < 32) red[tid] += red[tid + 32];
    __syncthreads();
    if (tid < 2) {
        int cnt = end - start;
        float inv = 1.0f / (float)(cnt > 0 ? cnt : 1);
        float o = bl[tid];
        for (int f2 = 0; f2 < 32; ++f2)
            o += red[f2] * inv * Wl[f2 * 2 + tid];
        out[g * 2 + tid] = o;
    }
}

extern "C" void kernel_launch(void* const* d_in, const int* in_sizes, int n_in,
                              void* d_out, int out_size, void* d_ws, size_t ws_size,
                              hipStream_t stream) {
    const float* x     = (const float*)d_in[0];
    const int*   ei    = (const int*)d_in[1];
    const float* ea    = (const float*)d_in[2];
    const int*   batch = (const int*)d_in[3];
    const float* W1 = (const float*)d_in[4];
    const float* b1 = (const float*)d_in[5];
    const float* W2 = (const float*)d_in[6];
    const float* b2 = (const float*)d_in[7];
    const float* W3 = (const float*)d_in[8];
    const float* b3 = (const float*)d_in[9];
    const float* Wl = (const float*)d_in[10];
    const float* bl = (const float*)d_in[11];
    float* out = (float*)d_out;
    float* ws  = (float*)d_ws;

    const int* src = ei;            // edge_index[0]
    const int* dst = ei + N_EDGES;  // edge_index[1]

    // workspace layout (floats)
    size_t off = 0;
    float* deg  = ws + off; off += N_NODES;
    float* dinv = ws + off; off += N_NODES;
    float* w    = ws + off; off += N_EDGES;
    float* bufA = ws + off; off += (size_t)N_NODES * 160;  // T1 scratch
    float* bufB = ws + off; off += (size_t)N_NODES * 160;  // T2 scratch
    float* bufC = ws + off; off += (size_t)N_NODES * 128;  // layer1 out / layer3 out
    float* bufD = ws + off; off += (size_t)N_NODES * 64;   // layer2 out

    const int BT = 256;
    // --- normalization ---
    hipMemsetAsync(deg, 0, N_NODES * sizeof(float), stream);
    deg_kernel<<<(N_EDGES + BT - 1) / BT, BT, 0, stream>>>(src, ea, deg, N_EDGES);
    dinv_kernel<<<(N_NODES + BT - 1) / BT, BT, 0, stream>>>(deg, dinv, N_NODES);
    edgew_kernel<<<(N_EDGES + BT - 1) / BT, BT, 0, stream>>>(src, dst, ea, dinv, w, N_EDGES);

    auto layer = [&](const float* T0, float* T1, float* T2, float* OUT,
                     const float* W, const float* b, int Fin, int Fout) {
        int jq = Fout / 4;
        long long mth = (long long)N_NODES * jq;
        int mgrid = (int)((mth + BT - 1) / BT);
        int Finq = Fin / 4;
        long long pth = (long long)N_EDGES * Finq;
        int pgrid = (int)((pth + BT - 1) / BT);
        size_t nodeBytes = (size_t)N_NODES * Fin * sizeof(float);
        long long c4 = (long long)N_NODES * Finq;
        int cgrid = (int)((c4 + BT - 1) / BT);

        // OUT = T0 @ W[0]
        matmul_kernel<<<mgrid, BT, 0, stream>>>(T0, W, OUT, N_NODES, Fin, Fout, 0);
        // T1 = L_hat @ T0
        hipMemsetAsync(T1, 0, nodeBytes, stream);
        propagate_kernel<<<pgrid, BT, 0, stream>>>(T0, src, dst, w, T1, N_EDGES, Finq);
        // OUT += T1 @ W[1]
        matmul_kernel<<<mgrid, BT, 0, stream>>>(T1, W + (size_t)Fin * Fout, OUT, N_NODES, Fin, Fout, 1);
        // T2 = 2 * L_hat @ T1 - T0
        hipMemsetAsync(T2, 0, nodeBytes, stream);
        propagate_kernel<<<pgrid, BT, 0, stream>>>(T1, src, dst, w, T2, N_EDGES, Finq);
        combine_kernel<<<cgrid, BT, 0, stream>>>(T2, T0, c4);
        // OUT += T2 @ W[2]; then bias+relu
        matmul_kernel<<<mgrid, BT, 0, stream>>>(T2, W + 2 * (size_t)Fin * Fout, OUT, N_NODES, Fin, Fout, 1);
        bias_relu_kernel<<<mgrid, BT, 0, stream>>>(OUT, b, N_NODES, Fout);
    };

    layer(x,    bufA, bufB, bufC, W1, b1, 160, 128);
    layer(bufC, bufA, bufB, bufD, W2, b2, 128, 64);
    layer(bufD, bufA, bufB, bufC, W3, b3, 64, 32);

    pool_kernel<<<NUM_G, BT, 0, stream>>>(bufC, batch, Wl, bl, out, N_NODES);
}

// Round 2
// 702.210 us; speedup vs baseline: 7.8782x; 7.8782x over previous
//
#include <hip/hip_runtime.h>

#define N_NODES 50000
#define N_EDGES 500000
#define NUM_G   128

// ---------------- setup: degree + dst histogram ----------------
__global__ void deg_count_kernel(const int* __restrict__ src, const int* __restrict__ dst,
                                 const float* __restrict__ ea,
                                 float* __restrict__ deg, int* __restrict__ cnt, int E) {
    int e = blockIdx.x * blockDim.x + threadIdx.x;
    if (e < E) {
        atomicAdd(&deg[src[e]], ea[e]);
        atomicAdd(&cnt[dst[e]], 1);
    }
}

__global__ void dinv_kernel(const float* __restrict__ deg, float* __restrict__ dinv, int n) {
    int i = blockIdx.x * blockDim.x + threadIdx.x;
    if (i >= n) return;
    float d = deg[i];
    float r = 0.0f;
    if (d > 0.0f) {
        r = rsqrtf(d);
        r = r * (1.5f - 0.5f * d * r * r);   // Newton refine to ~fp32 exact
    }
    dinv[i] = r;
}

// single-block exclusive scan of cnt[0..n) -> rowptr[0..n], rowptr[n]=total
__global__ void scan_kernel(const int* __restrict__ cnt, int* __restrict__ rowptr, int n) {
    const int T = 256;
    int tid = threadIdx.x;
    int ch = (n + T - 1) / T;
    int base = tid * ch;
    int end = min(base + ch, n);
    int s = 0;
    for (int i = base; i < end; ++i) s += cnt[i];
    __shared__ int red[T];
    red[tid] = s;
    __syncthreads();
    // Hillis-Steele inclusive scan
    for (int off = 1; off < T; off <<= 1) {
        int v = (tid >= off) ? red[tid - off] : 0;
        __syncthreads();
        red[tid] += v;
        __syncthreads();
    }
    int excl = (tid == 0) ? 0 : red[tid - 1];
    int run = excl;
    for (int i = base; i < end; ++i) {
        rowptr[i] = run;
        run += cnt[i];
    }
    if (tid == T - 1) rowptr[n] = red[T - 1];
}

__global__ void scatter_kernel(const int* __restrict__ src, const int* __restrict__ dst,
                               const float* __restrict__ ea, const float* __restrict__ dinv,
                               const int* __restrict__ rowptr, int* __restrict__ fill,
                               int* __restrict__ csr_src, float* __restrict__ csr_w, int E) {
    int e = blockIdx.x * blockDim.x + threadIdx.x;
    if (e >= E) return;
    int s = src[e], d = dst[e];
    float wv = -dinv[s] * ea[e] * dinv[d];
    int pos = rowptr[d] + atomicAdd(&fill[d], 1);
    csr_src[pos] = s;
    csr_w[pos] = wv;
}

// ---------------- CSR gather propagate ----------------
// mode 0: out[d] = sum_i w_i * X[src_i]
// mode 1: out[d] = 2*sum_i w_i * X[src_i] - T0[d]
__global__ void gather_kernel(const float* __restrict__ X, const int* __restrict__ csr_src,
                              const float* __restrict__ csr_w, const int* __restrict__ rowptr,
                              const float* __restrict__ T0, float* __restrict__ out,
                              int n, int Fq, int mode) {
    long long t = (long long)blockIdx.x * blockDim.x + threadIdx.x;
    int d = (int)(t / Fq);
    if (d >= n) return;
    int f4 = (int)(t % Fq) * 4;
    int F = Fq * 4;
    int beg = rowptr[d], end = rowptr[d + 1];
    float4 acc = make_float4(0.f, 0.f, 0.f, 0.f);
    for (int i = beg; i < end; ++i) {
        int s = csr_src[i];
        float wv = csr_w[i];
        const float4 xv = *reinterpret_cast<const float4*>(X + (size_t)s * F + f4);
        acc.x += wv * xv.x;
        acc.y += wv * xv.y;
        acc.z += wv * xv.z;
        acc.w += wv * xv.w;
    }
    if (mode) {
        const float4 t0 = *reinterpret_cast<const float4*>(T0 + (size_t)d * F + f4);
        acc.x = 2.f * acc.x - t0.x;
        acc.y = 2.f * acc.y - t0.y;
        acc.z = 2.f * acc.z - t0.z;
        acc.w = 2.f * acc.w - t0.w;
    }
    *reinterpret_cast<float4*>(out + (size_t)d * F + f4) = acc;
}

// ---------------- fused ChebConv GEMM: OUT = relu([T0;T1;T2] @ W + b) ----------------
// W is (3, Fin, FOUT) contiguous = (3*Fin, FOUT). 64-node tile, 32-k tile, LDS staged.
template<int FOUT>
__launch_bounds__(256)
__global__ void cheb_matmul(const float* __restrict__ T0, const float* __restrict__ T1,
                            const float* __restrict__ T2, const float* __restrict__ W,
                            const float* __restrict__ b, float* __restrict__ OUT,
                            int Fin, int nrows) {
    constexpr int TN = 64, TK = 32;
    constexpr int JQ = FOUT / 4;        // 32 / 16 / 8
    constexpr int ROWS = 256 / JQ;      // 8 / 16 / 32
    constexpr int NPT = TN / ROWS;      // 8 / 4 / 2
    __shared__ float As[TK][TN + 1];
    __shared__ float Ws[TK][FOUT];
    int tid = threadIdx.x;
    int tx = tid % JQ, ty = tid / JQ;
    int node0 = blockIdx.x * TN;
    float4 acc[NPT];
    #pragma unroll
    for (int m = 0; m < NPT; ++m) acc[m] = make_float4(0.f, 0.f, 0.f, 0.f);
    const float* mats[3] = {T0, T1, T2};
    int ktiles = (3 * Fin) / TK;
    for (int kt = 0; kt < ktiles; ++kt) {
        int kbase = kt * TK;
        int sel = kbase / Fin;
        const float* A = mats[sel];
        int ko = kbase - sel * Fin;
        // A tile: 64 rows x 32 cols -> As transposed; 2 float4 loads/thread
        #pragma unroll
        for (int q = 0; q < 2; ++q) {
            int lin = tid * 2 + q;          // 0..511
            int r = lin >> 3;               // row 0..63
            int c = (lin & 7) * 4;          // col quad base
            int row = node0 + r;
            float4 v = make_float4(0.f, 0.f, 0.f, 0.f);
            if (row < nrows)
                v = *reinterpret_cast<const float4*>(A + (size_t)row * Fin + ko + c);
            As[c + 0][r] = v.x;
            As[c + 1][r] = v.y;
            As[c + 2][r] = v.z;
            As[c + 3][r] = v.w;
        }
        // W tile: TK x FOUT floats, straight coalesced copy
        constexpr int WL = (TK * FOUT) / (4 * 256);   // 4 / 2 / 1 float4 per thread
        #pragma unroll
        for (int q = 0; q < WL; ++q) {
            int lin = tid + q * 256;        // float4 index
            int k = (lin * 4) / FOUT;
            int j = (lin * 4) % FOUT;
            *reinterpret_cast<float4*>(&Ws[k][j]) =
                *reinterpret_cast<const float4*>(W + (size_t)(kbase + k) * FOUT + j);
        }
        __syncthreads();
        #pragma unroll
        for (int kk = 0; kk < TK; ++kk) {
            float4 wv = *reinterpret_cast<float4*>(&Ws[kk][tx * 4]);
            #pragma unroll
            for (int m = 0; m < NPT; ++m) {
                float a = As[kk][ty + ROWS * m];
                acc[m].x += a * wv.x;
                acc[m].y += a * wv.y;
                acc[m].z += a * wv.z;
                acc[m].w += a * wv.w;
            }
        }
        __syncthreads();
    }
    float4 bv = *reinterpret_cast<const float4*>(b + tx * 4);
    #pragma unroll
    for (int m = 0; m < NPT; ++m) {
        int row = node0 + ty + ROWS * m;
        if (row < nrows) {
            float4 v;
            v.x = fmaxf(acc[m].x + bv.x, 0.f);
            v.y = fmaxf(acc[m].y + bv.y, 0.f);
            v.z = fmaxf(acc[m].z + bv.z, 0.f);
            v.w = fmaxf(acc[m].w + bv.w, 0.f);
            *reinterpret_cast<float4*>(OUT + (size_t)row * FOUT + tx * 4) = v;
        }
    }
}

// ---------------- pooling + final linear ----------------
__device__ __forceinline__ int lower_bound_dev(const int* __restrict__ a, int n, int v) {
    int lo = 0, hi = n;
    while (lo < hi) {
        int mid = (lo + hi) >> 1;
        if (a[mid] < v) lo = mid + 1; else hi = mid;
    }
    return lo;
}

__global__ void pool_kernel(const float* __restrict__ H, const int* __restrict__ batch,
                            const float* __restrict__ Wl, const float* __restrict__ bl,
                            float* __restrict__ out, int n) {
    int g = blockIdx.x;
    int start = lower_bound_dev(batch, n, g);
    int end   = lower_bound_dev(batch, n, g + 1);
    int tid = threadIdx.x;
    int f = tid & 31;
    int sub = tid >> 5;  // 0..7
    float acc = 0.0f;
    for (int i = start + sub; i < end; i += 8)
        acc += H[(size_t)i * 32 + f];
    __shared__ float red[256];
    red[tid] = acc;
    __syncthreads();
    if (tid < 128) red[tid] += red[tid + 128];
    __syncthreads();
    if (tid < 64) red[tid] += red[tid + 64];
    __syncthreads();
    if (tid < 32) red[tid] += red[tid + 32];
    __syncthreads();
    if (tid < 2) {
        int cnt = end - start;
        float inv = 1.0f / (float)(cnt > 0 ? cnt : 1);
        float o = bl[tid];
        for (int f2 = 0; f2 < 32; ++f2)
            o += red[f2] * inv * Wl[f2 * 2 + tid];
        out[g * 2 + tid] = o;
    }
}

extern "C" void kernel_launch(void* const* d_in, const int* in_sizes, int n_in,
                              void* d_out, int out_size, void* d_ws, size_t ws_size,
                              hipStream_t stream) {
    const float* x     = (const float*)d_in[0];
    const int*   ei    = (const int*)d_in[1];
    const float* ea    = (const float*)d_in[2];
    const int*   batch = (const int*)d_in[3];
    const float* W1 = (const float*)d_in[4];
    const float* b1 = (const float*)d_in[5];
    const float* W2 = (const float*)d_in[6];
    const float* b2 = (const float*)d_in[7];
    const float* W3 = (const float*)d_in[8];
    const float* b3 = (const float*)d_in[9];
    const float* Wl = (const float*)d_in[10];
    const float* bl = (const float*)d_in[11];
    float* out = (float*)d_out;
    char* ws = (char*)d_ws;

    const int* src = ei;            // edge_index[0]
    const int* dst = ei + N_EDGES;  // edge_index[1]

    // workspace layout
    size_t off = 0;
    auto alloc = [&](size_t bytes) { char* p = ws + off; off += (bytes + 255) & ~(size_t)255; return p; };
    float* deg     = (float*)alloc(N_NODES * 4);
    float* dinv    = (float*)alloc(N_NODES * 4);
    int*   cnt     = (int*)  alloc(N_NODES * 4);
    int*   rowptr  = (int*)  alloc((N_NODES + 1) * 4);
    int*   fill    = (int*)  alloc(N_NODES * 4);
    int*   csr_src = (int*)  alloc((size_t)N_EDGES * 4);
    float* csr_w   = (float*)alloc((size_t)N_EDGES * 4);
    float* bufA    = (float*)alloc((size_t)N_NODES * 160 * 4);
    float* bufB    = (float*)alloc((size_t)N_NODES * 160 * 4);
    float* bufC    = (float*)alloc((size_t)N_NODES * 128 * 4);
    float* bufD    = (float*)alloc((size_t)N_NODES * 64 * 4);

    const int BT = 256;
    // --- CSR build + normalization ---
    hipMemsetAsync(deg, 0, N_NODES * 4, stream);
    hipMemsetAsync(cnt, 0, N_NODES * 4, stream);
    hipMemsetAsync(fill, 0, N_NODES * 4, stream);
    deg_count_kernel<<<(N_EDGES + BT - 1) / BT, BT, 0, stream>>>(src, dst, ea, deg, cnt, N_EDGES);
    dinv_kernel<<<(N_NODES + BT - 1) / BT, BT, 0, stream>>>(deg, dinv, N_NODES);
    scan_kernel<<<1, BT, 0, stream>>>(cnt, rowptr, N_NODES);
    scatter_kernel<<<(N_EDGES + BT - 1) / BT, BT, 0, stream>>>(src, dst, ea, dinv, rowptr, fill,
                                                               csr_src, csr_w, N_EDGES);

    auto gather = [&](const float* X, const float* T0, float* outp, int F, int mode) {
        int Fq = F / 4;
        long long th = (long long)N_NODES * Fq;
        int grid = (int)((th + BT - 1) / BT);
        gather_kernel<<<grid, BT, 0, stream>>>(X, csr_src, csr_w, rowptr, T0, outp,
                                               N_NODES, Fq, mode);
    };
    int mgrid = (N_NODES + 63) / 64;

    // layer 1: 160 -> 128
    gather(x, nullptr, bufA, 160, 0);
    gather(bufA, x, bufB, 160, 1);
    cheb_matmul<128><<<mgrid, BT, 0, stream>>>(x, bufA, bufB, W1, b1, bufC, 160, N_NODES);
    // layer 2: 128 -> 64
    gather(bufC, nullptr, bufA, 128, 0);
    gather(bufA, bufC, bufB, 128, 1);
    cheb_matmul<64><<<mgrid, BT, 0, stream>>>(bufC, bufA, bufB, W2, b2, bufD, 128, N_NODES);
    // layer 3: 64 -> 32
    gather(bufD, nullptr, bufA, 64, 0);
    gather(bufA, bufD, bufB, 64, 1);
    cheb_matmul<32><<<mgrid, BT, 0, stream>>>(bufD, bufA, bufB, W3, b3, bufC, 64, N_NODES);

    pool_kernel<<<NUM_G, BT, 0, stream>>>(bufC, batch, Wl, bl, out, N_NODES);
}

// Round 3
// 479.526 us; speedup vs baseline: 11.5367x; 1.4644x over previous
//
#include <hip/hip_runtime.h>

#define N_NODES 50000
#define N_EDGES 500000
#define NUM_G   128

typedef __attribute__((ext_vector_type(8))) short short8;
typedef __attribute__((ext_vector_type(4))) float f32x4;

__device__ __forceinline__ unsigned f2bf(float x) {
    unsigned u = __float_as_uint(x);
    return (u + 0x7FFFu + ((u >> 16) & 1u)) >> 16;   // RNE
}
__device__ __forceinline__ float bf2f(unsigned h) {
    return __uint_as_float(h << 16);
}

// ---------------- setup: degree + dst histogram ----------------
__global__ void deg_count_kernel(const int* __restrict__ src, const int* __restrict__ dst,
                                 const float* __restrict__ ea,
                                 float* __restrict__ deg, int* __restrict__ cnt, int E) {
    int e = blockIdx.x * blockDim.x + threadIdx.x;
    if (e < E) {
        atomicAdd(&deg[src[e]], ea[e]);
        atomicAdd(&cnt[dst[e]], 1);
    }
}

__global__ void dinv_kernel(const float* __restrict__ deg, float* __restrict__ dinv, int n) {
    int i = blockIdx.x * blockDim.x + threadIdx.x;
    if (i >= n) return;
    float d = deg[i];
    float r = 0.0f;
    if (d > 0.0f) {
        r = rsqrtf(d);
        r = r * (1.5f - 0.5f * d * r * r);
    }
    dinv[i] = r;
}

__global__ void scan_kernel(const int* __restrict__ cnt, int* __restrict__ rowptr, int n) {
    const int T = 256;
    int tid = threadIdx.x;
    int ch = (n + T - 1) / T;
    int base = tid * ch;
    int end = min(base + ch, n);
    int s = 0;
    for (int i = base; i < end; ++i) s += cnt[i];
    __shared__ int red[T];
    red[tid] = s;
    __syncthreads();
    for (int off = 1; off < T; off <<= 1) {
        int v = (tid >= off) ? red[tid - off] : 0;
        __syncthreads();
        red[tid] += v;
        __syncthreads();
    }
    int run = (tid == 0) ? 0 : red[tid - 1];
    for (int i = base; i < end; ++i) {
        rowptr[i] = run;
        run += cnt[i];
    }
    if (tid == T - 1) rowptr[n] = red[T - 1];
}

__global__ void scatter_kernel(const int* __restrict__ src, const int* __restrict__ dst,
                               const float* __restrict__ ea, const float* __restrict__ dinv,
                               const int* __restrict__ rowptr, int* __restrict__ fill,
                               int* __restrict__ csr_src, float* __restrict__ csr_w, int E) {
    int e = blockIdx.x * blockDim.x + threadIdx.x;
    if (e >= E) return;
    int s = src[e], d = dst[e];
    float wv = -dinv[s] * ea[e] * dinv[d];
    int pos = rowptr[d] + atomicAdd(&fill[d], 1);
    csr_src[pos] = s;
    csr_w[pos] = wv;
}

// ---------------- fp32 -> bf16 conversion ----------------
__global__ void conv_bf16_kernel(const float* __restrict__ x, unsigned short* __restrict__ o, int n4) {
    int t = blockIdx.x * blockDim.x + threadIdx.x;
    if (t >= n4) return;
    float4 v = reinterpret_cast<const float4*>(x)[t];
    ushort4 r;
    r.x = (unsigned short)f2bf(v.x);
    r.y = (unsigned short)f2bf(v.y);
    r.z = (unsigned short)f2bf(v.z);
    r.w = (unsigned short)f2bf(v.w);
    *reinterpret_cast<ushort4*>(o + (size_t)t * 4) = r;
}

// Build WcatT bf16: WT[n][k], n in [0,3F), k in [0,FIN)
// col-block 0: W0 - W2, block 1: W1, block 2: W2.   W is (3, FIN, F) row-major fp32.
__global__ void wprep_kernel(const float* __restrict__ W, unsigned short* __restrict__ WT,
                             int FIN, int F) {
    int t = blockIdx.x * blockDim.x + threadIdx.x;
    int total = 3 * F * FIN;
    if (t >= total) return;
    int n = t / FIN, k = t - n * FIN;
    int sel = n / F, c = n - sel * F;
    float v;
    if (sel == 0) v = W[(size_t)k * F + c] - W[(size_t)2 * FIN * F + (size_t)k * F + c];
    else          v = W[(size_t)sel * FIN * F + (size_t)k * F + c];
    WT[t] = (unsigned short)f2bf(v);
}

// ---------------- MFMA GEMM: [Y0|Y1|Y2b] = Xb @ WcatT^T ----------------
// Xb: nrows x FIN bf16.  WT: (3F) x FIN bf16 (transposed weights).
// Block tile: M=128 (4 waves x 32), N=32.  K-step 32 via mfma_f32_16x16x32_bf16.
__launch_bounds__(256)
__global__ void cheb_gemm(const unsigned short* __restrict__ Xb, const unsigned short* __restrict__ WT,
                          float* __restrict__ Y0, float* __restrict__ Y1,
                          unsigned short* __restrict__ Y2b,
                          int FIN, int F, int nrows) {
    __shared__ short As[128][40];   // 32 k-cols padded to 40 (bank-conflict)
    __shared__ short Bs[32][40];
    int tid = threadIdx.x;
    int lane = tid & 63, w = tid >> 6;
    int m0 = blockIdx.x * 128;
    int n0 = blockIdx.y * 32;
    int sel = n0 / F;
    int lc0 = n0 - sel * F;

    f32x4 acc00 = {0.f, 0.f, 0.f, 0.f}, acc01 = acc00, acc10 = acc00, acc11 = acc00;

    int ktiles = FIN >> 5;
    for (int kt = 0; kt < ktiles; ++kt) {
        int k0 = kt << 5;
        // stage A: 128 rows x 32 bf16 = 512 spans of 16B
        #pragma unroll
        for (int q = 0; q < 2; ++q) {
            int span = tid + q * 256;
            int r = span >> 2, c8 = (span & 3) << 3;
            int row = m0 + r;
            uint4 v = make_uint4(0u, 0u, 0u, 0u);
            if (row < nrows)
                v = *reinterpret_cast<const uint4*>(Xb + (size_t)row * FIN + k0 + c8);
            *reinterpret_cast<uint4*>(&As[r][c8]) = v;
        }
        // stage B: 32 rows x 32 bf16 = 128 spans
        if (tid < 128) {
            int r = tid >> 2, c8 = (tid & 3) << 3;
            *reinterpret_cast<uint4*>(&Bs[r][c8]) =
                *reinterpret_cast<const uint4*>(WT + (size_t)(n0 + r) * FIN + k0 + c8);
        }
        __syncthreads();
        int q8 = (lane >> 4) << 3;
        int mrow = (lane & 15) + w * 32;
        short8 a0 = *reinterpret_cast<const short8*>(&As[mrow][q8]);
        short8 a1 = *reinterpret_cast<const short8*>(&As[mrow + 16][q8]);
        short8 b0 = *reinterpret_cast<const short8*>(&Bs[lane & 15][q8]);
        short8 b1 = *reinterpret_cast<const short8*>(&Bs[(lane & 15) + 16][q8]);
        acc00 = __builtin_amdgcn_mfma_f32_16x16x32_bf16(a0, b0, acc00, 0, 0, 0);
        acc01 = __builtin_amdgcn_mfma_f32_16x16x32_bf16(a0, b1, acc01, 0, 0, 0);
        acc10 = __builtin_amdgcn_mfma_f32_16x16x32_bf16(a1, b0, acc10, 0, 0, 0);
        acc11 = __builtin_amdgcn_mfma_f32_16x16x32_bf16(a1, b1, acc11, 0, 0, 0);
        __syncthreads();
    }

    // epilogue: C/D layout col=lane&15, row=(lane>>4)*4+reg  [m89]
    int colb = lane & 15;
    int rq = (lane >> 4) << 2;
    f32x4 accs[2][2] = {{acc00, acc01}, {acc10, acc11}};
    #pragma unroll
    for (int mt = 0; mt < 2; ++mt) {
        #pragma unroll
        for (int nt = 0; nt < 2; ++nt) {
            #pragma unroll
            for (int r = 0; r < 4; ++r) {
                int row = m0 + w * 32 + mt * 16 + rq + r;
                if (row >= nrows) continue;
                int lc = lc0 + nt * 16 + colb;
                float v = accs[mt][nt][r];
                if (sel == 0)      Y0[(size_t)row * F + lc] = v;
                else if (sel == 1) Y1[(size_t)row * F + lc] = v;
                else               Y2b[(size_t)row * F + lc] = (unsigned short)f2bf(v);
            }
        }
    }
}

// ---------------- bf16 CSR gathers with fused epilogues ----------------
__device__ __forceinline__ void acc8(float* acc, uint4 p, float wv) {
    acc[0] += wv * bf2f(p.x << 16 >> 16);  // low 16
    acc[1] += wv * __uint_as_float(p.x & 0xFFFF0000u);
    acc[2] += wv * bf2f(p.y & 0xFFFFu);
    acc[3] += wv * __uint_as_float(p.y & 0xFFFF0000u);
    acc[4] += wv * bf2f(p.z & 0xFFFFu);
    acc[5] += wv * __uint_as_float(p.z & 0xFFFF0000u);
    acc[6] += wv * bf2f(p.w & 0xFFFFu);
    acc[7] += wv * __uint_as_float(p.w & 0xFFFF0000u);
}

// Z = P(Y2b);  U = bf16(Y1 + 2Z)
__global__ void gather_z_kernel(const unsigned short* __restrict__ X, const int* __restrict__ csr_src,
                                const float* __restrict__ csr_w, const int* __restrict__ rowptr,
                                const float* __restrict__ Y1, unsigned short* __restrict__ U,
                                int n, int F) {
    int Fq8 = F >> 3;
    int t = blockIdx.x * blockDim.x + threadIdx.x;
    int d = t / Fq8;
    if (d >= n) return;
    int f8 = (t - d * Fq8) << 3;
    int beg = rowptr[d], end = rowptr[d + 1];
    float acc[8] = {0.f, 0.f, 0.f, 0.f, 0.f, 0.f, 0.f, 0.f};
    int i = beg;
    for (; i + 1 < end; i += 2) {
        int s0 = csr_src[i], s1 = csr_src[i + 1];
        float w0 = csr_w[i], w1 = csr_w[i + 1];
        uint4 p0 = *reinterpret_cast<const uint4*>(X + (size_t)s0 * F + f8);
        uint4 p1 = *reinterpret_cast<const uint4*>(X + (size_t)s1 * F + f8);
        acc8(acc, p0, w0);
        acc8(acc, p1, w1);
    }
    if (i < end) {
        int s0 = csr_src[i];
        float w0 = csr_w[i];
        uint4 p0 = *reinterpret_cast<const uint4*>(X + (size_t)s0 * F + f8);
        acc8(acc, p0, w0);
    }
    const float* y1 = Y1 + (size_t)d * F + f8;
    float4 ya = *reinterpret_cast<const float4*>(y1);
    float4 yb = *reinterpret_cast<const float4*>(y1 + 4);
    uint4 o;
    o.x = f2bf(ya.x + 2.f * acc[0]) | (f2bf(ya.y + 2.f * acc[1]) << 16);
    o.y = f2bf(ya.z + 2.f * acc[2]) | (f2bf(ya.w + 2.f * acc[3]) << 16);
    o.z = f2bf(yb.x + 2.f * acc[4]) | (f2bf(yb.y + 2.f * acc[5]) << 16);
    o.w = f2bf(yb.z + 2.f * acc[6]) | (f2bf(yb.w + 2.f * acc[7]) << 16);
    *reinterpret_cast<uint4*>(U + (size_t)d * F + f8) = o;
}

// V = P(U);  Xn = bf16(relu(Y0 + V + b))
__global__ void gather_v_kernel(const unsigned short* __restrict__ X, const int* __restrict__ csr_src,
                                const float* __restrict__ csr_w, const int* __restrict__ rowptr,
                                const float* __restrict__ Y0, const float* __restrict__ bias,
                                unsigned short* __restrict__ Xn, int n, int F) {
    int Fq8 = F >> 3;
    int t = blockIdx.x * blockDim.x + threadIdx.x;
    int d = t / Fq8;
    if (d >= n) return;
    int f8 = (t - d * Fq8) << 3;
    int beg = rowptr[d], end = rowptr[d + 1];
    float acc[8] = {0.f, 0.f, 0.f, 0.f, 0.f, 0.f, 0.f, 0.f};
    int i = beg;
    for (; i + 1 < end; i += 2) {
        int s0 = csr_src[i], s1 = csr_src[i + 1];
        float w0 = csr_w[i], w1 = csr_w[i + 1];
        uint4 p0 = *reinterpret_cast<const uint4*>(X + (size_t)s0 * F + f8);
        uint4 p1 = *reinterpret_cast<const uint4*>(X + (size_t)s1 * F + f8);
        acc8(acc, p0, w0);
        acc8(acc, p1, w1);
    }
    if (i < end) {
        int s0 = csr_src[i];
        float w0 = csr_w[i];
        uint4 p0 = *reinterpret_cast<const uint4*>(X + (size_t)s0 * F + f8);
        acc8(acc, p0, w0);
    }
    const float* y0 = Y0 + (size_t)d * F + f8;
    float4 ya = *reinterpret_cast<const float4*>(y0);
    float4 yb = *reinterpret_cast<const float4*>(y0 + 4);
    float4 ba = *reinterpret_cast<const float4*>(bias + f8);
    float4 bb = *reinterpret_cast<const float4*>(bias + f8 + 4);
    float v0 = fmaxf(ya.x + acc[0] + ba.x, 0.f);
    float v1 = fmaxf(ya.y + acc[1] + ba.y, 0.f);
    float v2 = fmaxf(ya.z + acc[2] + ba.z, 0.f);
    float v3 = fmaxf(ya.w + acc[3] + ba.w, 0.f);
    float v4 = fmaxf(yb.x + acc[4] + bb.x, 0.f);
    float v5 = fmaxf(yb.y + acc[5] + bb.y, 0.f);
    float v6 = fmaxf(yb.z + acc[6] + bb.z, 0.f);
    float v7 = fmaxf(yb.w + acc[7] + bb.w, 0.f);
    uint4 o;
    o.x = f2bf(v0) | (f2bf(v1) << 16);
    o.y = f2bf(v2) | (f2bf(v3) << 16);
    o.z = f2bf(v4) | (f2bf(v5) << 16);
    o.w = f2bf(v6) | (f2bf(v7) << 16);
    *reinterpret_cast<uint4*>(Xn + (size_t)d * F + f8) = o;
}

// ---------------- pooling + final linear ----------------
__device__ __forceinline__ int lower_bound_dev(const int* __restrict__ a, int n, int v) {
    int lo = 0, hi = n;
    while (lo < hi) {
        int mid = (lo + hi) >> 1;
        if (a[mid] < v) lo = mid + 1; else hi = mid;
    }
    return lo;
}

__global__ void pool_kernel(const unsigned short* __restrict__ H, const int* __restrict__ batch,
                            const float* __restrict__ Wl, const float* __restrict__ bl,
                            float* __restrict__ out, int n) {
    int g = blockIdx.x;
    int start = lower_bound_dev(batch, n, g);
    int end   = lower_bound_dev(batch, n, g + 1);
    int tid = threadIdx.x;
    int f = tid & 31;
    int sub = tid >> 5;
    float acc = 0.0f;
    for (int i = start + sub; i < end; i += 8)
        acc += bf2f((unsigned)H[(size_t)i * 32 + f]);
    __shared__ float red[256];
    red[tid] = acc;
    __syncthreads();
    if (tid < 128) red[tid] += red[tid + 128];
    __syncthreads();
    if (tid < 64) red[tid] += red[tid + 64];
    __syncthreads();
    if (tid < 32) red[tid] += red[tid + 32];
    __syncthreads();
    if (tid < 2) {
        int cnt = end - start;
        float inv = 1.0f / (float)(cnt > 0 ? cnt : 1);
        float o = bl[tid];
        for (int f2 = 0; f2 < 32; ++f2)
            o += red[f2] * inv * Wl[f2 * 2 + tid];
        out[g * 2 + tid] = o;
    }
}

extern "C" void kernel_launch(void* const* d_in, const int* in_sizes, int n_in,
                              void* d_out, int out_size, void* d_ws, size_t ws_size,
                              hipStream_t stream) {
    const float* x     = (const float*)d_in[0];
    const int*   ei    = (const int*)d_in[1];
    const float* ea    = (const float*)d_in[2];
    const int*   batch = (const int*)d_in[3];
    const float* W1 = (const float*)d_in[4];
    const float* b1 = (const float*)d_in[5];
    const float* W2 = (const float*)d_in[6];
    const float* b2 = (const float*)d_in[7];
    const float* W3 = (const float*)d_in[8];
    const float* b3 = (const float*)d_in[9];
    const float* Wl = (const float*)d_in[10];
    const float* bl = (const float*)d_in[11];
    float* out = (float*)d_out;
    char* ws = (char*)d_ws;

    const int* src = ei;
    const int* dst = ei + N_EDGES;

    size_t off = 0;
    auto alloc = [&](size_t bytes) { char* p = ws + off; off += (bytes + 255) & ~(size_t)255; return p; };
    float* deg     = (float*)alloc(N_NODES * 4);
    float* dinv    = (float*)alloc(N_NODES * 4);
    int*   cnt     = (int*)  alloc(N_NODES * 4);
    int*   rowptr  = (int*)  alloc((N_NODES + 1) * 4);
    int*   fill    = (int*)  alloc(N_NODES * 4);
    int*   csr_src = (int*)  alloc((size_t)N_EDGES * 4);
    float* csr_w   = (float*)alloc((size_t)N_EDGES * 4);
    unsigned short* Xb  = (unsigned short*)alloc((size_t)N_NODES * 160 * 2);  // layer input bf16
    float* Y0  = (float*)alloc((size_t)N_NODES * 128 * 4);
    float* Y1  = (float*)alloc((size_t)N_NODES * 128 * 4);
    unsigned short* Y2b = (unsigned short*)alloc((size_t)N_NODES * 128 * 2);
    unsigned short* U   = (unsigned short*)alloc((size_t)N_NODES * 128 * 2);
    unsigned short* WT1 = (unsigned short*)alloc((size_t)384 * 160 * 2);
    unsigned short* WT2 = (unsigned short*)alloc((size_t)192 * 128 * 2);
    unsigned short* WT3 = (unsigned short*)alloc((size_t)96 * 64 * 2);

    const int BT = 256;
    hipMemsetAsync(deg, 0, N_NODES * 4, stream);
    hipMemsetAsync(cnt, 0, N_NODES * 4, stream);
    hipMemsetAsync(fill, 0, N_NODES * 4, stream);
    deg_count_kernel<<<(N_EDGES + BT - 1) / BT, BT, 0, stream>>>(src, dst, ea, deg, cnt, N_EDGES);
    dinv_kernel<<<(N_NODES + BT - 1) / BT, BT, 0, stream>>>(deg, dinv, N_NODES);
    scan_kernel<<<1, BT, 0, stream>>>(cnt, rowptr, N_NODES);
    scatter_kernel<<<(N_EDGES + BT - 1) / BT, BT, 0, stream>>>(src, dst, ea, dinv, rowptr, fill,
                                                               csr_src, csr_w, N_EDGES);
    // x -> bf16
    int n4 = N_NODES * 160 / 4;
    conv_bf16_kernel<<<(n4 + BT - 1) / BT, BT, 0, stream>>>(x, Xb, n4);
    // weight prep
    wprep_kernel<<<(3 * 128 * 160 + BT - 1) / BT, BT, 0, stream>>>(W1, WT1, 160, 128);
    wprep_kernel<<<(3 * 64 * 128 + BT - 1) / BT, BT, 0, stream>>>(W2, WT2, 128, 64);
    wprep_kernel<<<(3 * 32 * 64 + BT - 1) / BT, BT, 0, stream>>>(W3, WT3, 64, 32);

    auto layer = [&](const unsigned short* WT, const float* bias, int FIN, int F) {
        dim3 ggrid((N_NODES + 127) / 128, (3 * F) / 32);
        cheb_gemm<<<ggrid, BT, 0, stream>>>(Xb, WT, Y0, Y1, Y2b, FIN, F, N_NODES);
        int gth = N_NODES * (F / 8);
        int ggr = (gth + BT - 1) / BT;
        gather_z_kernel<<<ggr, BT, 0, stream>>>(Y2b, csr_src, csr_w, rowptr, Y1, U, N_NODES, F);
        gather_v_kernel<<<ggr, BT, 0, stream>>>(U, csr_src, csr_w, rowptr, Y0, bias, Xb, N_NODES, F);
    };

    layer(WT1, b1, 160, 128);
    layer(WT2, b2, 128, 64);
    layer(WT3, b3, 64, 32);

    pool_kernel<<<NUM_G, BT, 0, stream>>>(Xb, batch, Wl, bl, out, N_NODES);
}

// Round 4
// 403.778 us; speedup vs baseline: 13.7010x; 1.1876x over previous
//
#include <hip/hip_runtime.h>

#define N_NODES 50000
#define N_EDGES 500000
#define NUM_G   128
#define SCAN_NB 49              // ceil(50000/1024)
#define SCAN_PAD (SCAN_NB * 1024)

typedef __attribute__((ext_vector_type(8))) short short8;
typedef __attribute__((ext_vector_type(4))) float f32x4;

__device__ __forceinline__ unsigned f2bf(float x) {
    unsigned u = __float_as_uint(x);
    return (u + 0x7FFFu + ((u >> 16) & 1u)) >> 16;   // RNE
}
__device__ __forceinline__ float bf2f(unsigned h) {
    return __uint_as_float(h << 16);
}

// ---------------- setup: degree + dst histogram ----------------
__global__ void deg_count_kernel(const int* __restrict__ src, const int* __restrict__ dst,
                                 const float* __restrict__ ea,
                                 float* __restrict__ deg, int* __restrict__ cnt, int E) {
    int e = blockIdx.x * blockDim.x + threadIdx.x;
    if (e < E) {
        atomicAdd(&deg[src[e]], ea[e]);
        atomicAdd(&cnt[dst[e]], 1);
    }
}

__global__ void dinv_kernel(const float* __restrict__ deg, float* __restrict__ dinv, int n) {
    int i = blockIdx.x * blockDim.x + threadIdx.x;
    if (i >= n) return;
    float d = deg[i];
    float r = 0.0f;
    if (d > 0.0f) {
        r = rsqrtf(d);
        r = r * (1.5f - 0.5f * d * r * r);
    }
    dinv[i] = r;
}

// ---------------- 3-phase scan: cnt (padded, zeroed) -> rowptr ----------------
__global__ void scan_partial_kernel(const int* __restrict__ cnt, int* __restrict__ partial) {
    int b = blockIdx.x, t = threadIdx.x;
    int4 v = reinterpret_cast<const int4*>(cnt)[b * 256 + t];
    int s = v.x + v.y + v.z + v.w;
    __shared__ int red[256];
    red[t] = s;
    __syncthreads();
    for (int off = 128; off > 0; off >>= 1) {
        if (t < off) red[t] += red[t + off];
        __syncthreads();
    }
    if (t == 0) partial[b] = red[0];
}

__global__ void scan_offsets_kernel(int* __restrict__ partial, int* __restrict__ rowptr,
                                    int nb, int n) {
    int t = threadIdx.x;  // single wave of 64
    int orig = (t < nb) ? partial[t] : 0;
    int v = orig;
    for (int off = 1; off < 64; off <<= 1) {
        int u = __shfl_up(v, off, 64);
        if (t >= off) v += u;
    }
    if (t < nb) partial[t] = v - orig;   // exclusive offset
    if (t == nb - 1) rowptr[n] = v;      // total
}

__global__ void scan_final_kernel(const int* __restrict__ cnt, const int* __restrict__ partial,
                                  int* __restrict__ rowptr, int n) {
    int b = blockIdx.x, t = threadIdx.x;
    int4 v = reinterpret_cast<const int4*>(cnt)[b * 256 + t];
    int s = v.x + v.y + v.z + v.w;
    __shared__ int red[256];
    red[t] = s;
    __syncthreads();
    for (int off = 1; off < 256; off <<= 1) {
        int u = (t >= off) ? red[t - off] : 0;
        __syncthreads();
        red[t] += u;
        __syncthreads();
    }
    int excl = partial[b] + ((t == 0) ? 0 : red[t - 1]);
    int i0 = b * 1024 + t * 4;
    if (i0 < n)     rowptr[i0]     = excl;
    if (i0 + 1 < n) rowptr[i0 + 1] = excl + v.x;
    if (i0 + 2 < n) rowptr[i0 + 2] = excl + v.x + v.y;
    if (i0 + 3 < n) rowptr[i0 + 3] = excl + v.x + v.y + v.z;
}

__global__ void scatter_kernel(const int* __restrict__ src, const int* __restrict__ dst,
                               const float* __restrict__ ea, const float* __restrict__ dinv,
                               const int* __restrict__ rowptr, int* __restrict__ fill,
                               int* __restrict__ csr_src, float* __restrict__ csr_w, int E) {
    int e = blockIdx.x * blockDim.x + threadIdx.x;
    if (e >= E) return;
    int s = src[e], d = dst[e];
    float wv = -dinv[s] * ea[e] * dinv[d];
    int pos = rowptr[d] + atomicAdd(&fill[d], 1);
    csr_src[pos] = s;
    csr_w[pos] = wv;
}

// ---------------- fp32 -> bf16 conversion ----------------
__global__ void conv_bf16_kernel(const float* __restrict__ x, unsigned short* __restrict__ o, int n4) {
    int t = blockIdx.x * blockDim.x + threadIdx.x;
    if (t >= n4) return;
    float4 v = reinterpret_cast<const float4*>(x)[t];
    ushort4 r;
    r.x = (unsigned short)f2bf(v.x);
    r.y = (unsigned short)f2bf(v.y);
    r.z = (unsigned short)f2bf(v.z);
    r.w = (unsigned short)f2bf(v.w);
    *reinterpret_cast<ushort4*>(o + (size_t)t * 4) = r;
}

// Build WcatT bf16: WT[n][k], n in [0,3F), k in [0,FIN)
__global__ void wprep_kernel(const float* __restrict__ W, unsigned short* __restrict__ WT,
                             int FIN, int F) {
    int t = blockIdx.x * blockDim.x + threadIdx.x;
    int total = 3 * F * FIN;
    if (t >= total) return;
    int n = t / FIN, k = t - n * FIN;
    int sel = n / F, c = n - sel * F;
    float v;
    if (sel == 0) v = W[(size_t)k * F + c] - W[(size_t)2 * FIN * F + (size_t)k * F + c];
    else          v = W[(size_t)sel * FIN * F + (size_t)k * F + c];
    WT[t] = (unsigned short)f2bf(v);
}

// ---------------- MFMA GEMM: [Y0|Y1|Y2b] = Xb @ WcatT^T ----------------
__launch_bounds__(256)
__global__ void cheb_gemm(const unsigned short* __restrict__ Xb, const unsigned short* __restrict__ WT,
                          float* __restrict__ Y0, float* __restrict__ Y1,
                          unsigned short* __restrict__ Y2b,
                          int FIN, int F, int nrows) {
    __shared__ short As[128][40];
    __shared__ short Bs[32][40];
    int tid = threadIdx.x;
    int lane = tid & 63, w = tid >> 6;
    int m0 = blockIdx.x * 128;
    int n0 = blockIdx.y * 32;
    int sel = n0 / F;
    int lc0 = n0 - sel * F;

    f32x4 acc00 = {0.f, 0.f, 0.f, 0.f}, acc01 = acc00, acc10 = acc00, acc11 = acc00;

    int ktiles = FIN >> 5;
    for (int kt = 0; kt < ktiles; ++kt) {
        int k0 = kt << 5;
        #pragma unroll
        for (int q = 0; q < 2; ++q) {
            int span = tid + q * 256;
            int r = span >> 2, c8 = (span & 3) << 3;
            int row = m0 + r;
            uint4 v = make_uint4(0u, 0u, 0u, 0u);
            if (row < nrows)
                v = *reinterpret_cast<const uint4*>(Xb + (size_t)row * FIN + k0 + c8);
            *reinterpret_cast<uint4*>(&As[r][c8]) = v;
        }
        if (tid < 128) {
            int r = tid >> 2, c8 = (tid & 3) << 3;
            *reinterpret_cast<uint4*>(&Bs[r][c8]) =
                *reinterpret_cast<const uint4*>(WT + (size_t)(n0 + r) * FIN + k0 + c8);
        }
        __syncthreads();
        int q8 = (lane >> 4) << 3;
        int mrow = (lane & 15) + w * 32;
        short8 a0 = *reinterpret_cast<const short8*>(&As[mrow][q8]);
        short8 a1 = *reinterpret_cast<const short8*>(&As[mrow + 16][q8]);
        short8 b0 = *reinterpret_cast<const short8*>(&Bs[lane & 15][q8]);
        short8 b1 = *reinterpret_cast<const short8*>(&Bs[(lane & 15) + 16][q8]);
        acc00 = __builtin_amdgcn_mfma_f32_16x16x32_bf16(a0, b0, acc00, 0, 0, 0);
        acc01 = __builtin_amdgcn_mfma_f32_16x16x32_bf16(a0, b1, acc01, 0, 0, 0);
        acc10 = __builtin_amdgcn_mfma_f32_16x16x32_bf16(a1, b0, acc10, 0, 0, 0);
        acc11 = __builtin_amdgcn_mfma_f32_16x16x32_bf16(a1, b1, acc11, 0, 0, 0);
        __syncthreads();
    }

    int colb = lane & 15;
    int rq = (lane >> 4) << 2;
    f32x4 accs[2][2] = {{acc00, acc01}, {acc10, acc11}};
    #pragma unroll
    for (int mt = 0; mt < 2; ++mt) {
        #pragma unroll
        for (int nt = 0; nt < 2; ++nt) {
            #pragma unroll
            for (int r = 0; r < 4; ++r) {
                int row = m0 + w * 32 + mt * 16 + rq + r;
                if (row >= nrows) continue;
                int lc = lc0 + nt * 16 + colb;
                float v = accs[mt][nt][r];
                if (sel == 0)      Y0[(size_t)row * F + lc] = v;
                else if (sel == 1) Y1[(size_t)row * F + lc] = v;
                else               Y2b[(size_t)row * F + lc] = (unsigned short)f2bf(v);
            }
        }
    }
}

// ---------------- bf16 CSR gathers with fused epilogues ----------------
__device__ __forceinline__ void acc8(float* acc, uint4 p, float wv) {
    acc[0] += wv * bf2f(p.x & 0xFFFFu);
    acc[1] += wv * __uint_as_float(p.x & 0xFFFF0000u);
    acc[2] += wv * bf2f(p.y & 0xFFFFu);
    acc[3] += wv * __uint_as_float(p.y & 0xFFFF0000u);
    acc[4] += wv * bf2f(p.z & 0xFFFFu);
    acc[5] += wv * __uint_as_float(p.z & 0xFFFF0000u);
    acc[6] += wv * bf2f(p.w & 0xFFFFu);
    acc[7] += wv * __uint_as_float(p.w & 0xFFFF0000u);
}

// Z = P(Y2b);  U = bf16(Y1 + 2Z)
__global__ void gather_z_kernel(const unsigned short* __restrict__ X, const int* __restrict__ csr_src,
                                const float* __restrict__ csr_w, const int* __restrict__ rowptr,
                                const float* __restrict__ Y1, unsigned short* __restrict__ U,
                                int n, int F) {
    int Fq8 = F >> 3;
    int t = blockIdx.x * blockDim.x + threadIdx.x;
    int d = t / Fq8;
    if (d >= n) return;
    int f8 = (t - d * Fq8) << 3;
    int beg = rowptr[d], end = rowptr[d + 1];
    float acc[8] = {0.f, 0.f, 0.f, 0.f, 0.f, 0.f, 0.f, 0.f};
    int i = beg;
    for (; i + 1 < end; i += 2) {
        int s0 = csr_src[i], s1 = csr_src[i + 1];
        float w0 = csr_w[i], w1 = csr_w[i + 1];
        uint4 p0 = *reinterpret_cast<const uint4*>(X + (size_t)s0 * F + f8);
        uint4 p1 = *reinterpret_cast<const uint4*>(X + (size_t)s1 * F + f8);
        acc8(acc, p0, w0);
        acc8(acc, p1, w1);
    }
    if (i < end) {
        int s0 = csr_src[i];
        float w0 = csr_w[i];
        uint4 p0 = *reinterpret_cast<const uint4*>(X + (size_t)s0 * F + f8);
        acc8(acc, p0, w0);
    }
    const float* y1 = Y1 + (size_t)d * F + f8;
    float4 ya = *reinterpret_cast<const float4*>(y1);
    float4 yb = *reinterpret_cast<const float4*>(y1 + 4);
    uint4 o;
    o.x = f2bf(ya.x + 2.f * acc[0]) | (f2bf(ya.y + 2.f * acc[1]) << 16);
    o.y = f2bf(ya.z + 2.f * acc[2]) | (f2bf(ya.w + 2.f * acc[3]) << 16);
    o.z = f2bf(yb.x + 2.f * acc[4]) | (f2bf(yb.y + 2.f * acc[5]) << 16);
    o.w = f2bf(yb.z + 2.f * acc[6]) | (f2bf(yb.w + 2.f * acc[7]) << 16);
    *reinterpret_cast<uint4*>(U + (size_t)d * F + f8) = o;
}

// V = P(U);  Xn = bf16(relu(Y0 + V + b))
__global__ void gather_v_kernel(const unsigned short* __restrict__ X, const int* __restrict__ csr_src,
                                const float* __restrict__ csr_w, const int* __restrict__ rowptr,
                                const float* __restrict__ Y0, const float* __restrict__ bias,
                                unsigned short* __restrict__ Xn, int n, int F) {
    int Fq8 = F >> 3;
    int t = blockIdx.x * blockDim.x + threadIdx.x;
    int d = t / Fq8;
    if (d >= n) return;
    int f8 = (t - d * Fq8) << 3;
    int beg = rowptr[d], end = rowptr[d + 1];
    float acc[8] = {0.f, 0.f, 0.f, 0.f, 0.f, 0.f, 0.f, 0.f};
    int i = beg;
    for (; i + 1 < end; i += 2) {
        int s0 = csr_src[i], s1 = csr_src[i + 1];
        float w0 = csr_w[i], w1 = csr_w[i + 1];
        uint4 p0 = *reinterpret_cast<const uint4*>(X + (size_t)s0 * F + f8);
        uint4 p1 = *reinterpret_cast<const uint4*>(X + (size_t)s1 * F + f8);
        acc8(acc, p0, w0);
        acc8(acc, p1, w1);
    }
    if (i < end) {
        int s0 = csr_src[i];
        float w0 = csr_w[i];
        uint4 p0 = *reinterpret_cast<const uint4*>(X + (size_t)s0 * F + f8);
        acc8(acc, p0, w0);
    }
    const float* y0 = Y0 + (size_t)d * F + f8;
    float4 ya = *reinterpret_cast<const float4*>(y0);
    float4 yb = *reinterpret_cast<const float4*>(y0 + 4);
    float4 ba = *reinterpret_cast<const float4*>(bias + f8);
    float4 bb = *reinterpret_cast<const float4*>(bias + f8 + 4);
    float v0 = fmaxf(ya.x + acc[0] + ba.x, 0.f);
    float v1 = fmaxf(ya.y + acc[1] + ba.y, 0.f);
    float v2 = fmaxf(ya.z + acc[2] + ba.z, 0.f);
    float v3 = fmaxf(ya.w + acc[3] + ba.w, 0.f);
    float v4 = fmaxf(yb.x + acc[4] + bb.x, 0.f);
    float v5 = fmaxf(yb.y + acc[5] + bb.y, 0.f);
    float v6 = fmaxf(yb.z + acc[6] + bb.z, 0.f);
    float v7 = fmaxf(yb.w + acc[7] + bb.w, 0.f);
    uint4 o;
    o.x = f2bf(v0) | (f2bf(v1) << 16);
    o.y = f2bf(v2) | (f2bf(v3) << 16);
    o.z = f2bf(v4) | (f2bf(v5) << 16);
    o.w = f2bf(v6) | (f2bf(v7) << 16);
    *reinterpret_cast<uint4*>(Xn + (size_t)d * F + f8) = o;
}

// ---------------- pooling + final linear ----------------
__device__ __forceinline__ int lower_bound_dev(const int* __restrict__ a, int n, int v) {
    int lo = 0, hi = n;
    while (lo < hi) {
        int mid = (lo + hi) >> 1;
        if (a[mid] < v) lo = mid + 1; else hi = mid;
    }
    return lo;
}

__global__ void pool_kernel(const unsigned short* __restrict__ H, const int* __restrict__ batch,
                            const float* __restrict__ Wl, const float* __restrict__ bl,
                            float* __restrict__ out, int n) {
    int g = blockIdx.x;
    int start = lower_bound_dev(batch, n, g);
    int end   = lower_bound_dev(batch, n, g + 1);
    int tid = threadIdx.x;
    int f = tid & 31;
    int sub = tid >> 5;
    float acc = 0.0f;
    for (int i = start + sub; i < end; i += 8)
        acc += bf2f((unsigned)H[(size_t)i * 32 + f]);
    __shared__ float red[256];
    red[tid] = acc;
    __syncthreads();
    if (tid < 128) red[tid] += red[tid + 128];
    __syncthreads();
    if (tid < 64) red[tid] += red[tid + 64];
    __syncthreads();
    if (tid < 32) red[tid] += red[tid + 32];
    __syncthreads();
    if (tid < 2) {
        int cnt = end - start;
        float inv = 1.0f / (float)(cnt > 0 ? cnt : 1);
        float o = bl[tid];
        for (int f2 = 0; f2 < 32; ++f2)
            o += red[f2] * inv * Wl[f2 * 2 + tid];
        out[g * 2 + tid] = o;
    }
}

extern "C" void kernel_launch(void* const* d_in, const int* in_sizes, int n_in,
                              void* d_out, int out_size, void* d_ws, size_t ws_size,
                              hipStream_t stream) {
    const float* x     = (const float*)d_in[0];
    const int*   ei    = (const int*)d_in[1];
    const float* ea    = (const float*)d_in[2];
    const int*   batch = (const int*)d_in[3];
    const float* W1 = (const float*)d_in[4];
    const float* b1 = (const float*)d_in[5];
    const float* W2 = (const float*)d_in[6];
    const float* b2 = (const float*)d_in[7];
    const float* W3 = (const float*)d_in[8];
    const float* b3 = (const float*)d_in[9];
    const float* Wl = (const float*)d_in[10];
    const float* bl = (const float*)d_in[11];
    float* out = (float*)d_out;
    char* ws = (char*)d_ws;

    const int* src = ei;
    const int* dst = ei + N_EDGES;

    size_t off = 0;
    auto alloc = [&](size_t bytes) { char* p = ws + off; off += (bytes + 255) & ~(size_t)255; return p; };
    float* deg     = (float*)alloc(N_NODES * 4);
    float* dinv    = (float*)alloc(N_NODES * 4);
    int*   cnt     = (int*)  alloc((size_t)SCAN_PAD * 4);
    int*   partial = (int*)  alloc(SCAN_NB * 4);
    int*   rowptr  = (int*)  alloc((N_NODES + 1) * 4);
    int*   fill    = (int*)  alloc(N_NODES * 4);
    int*   csr_src = (int*)  alloc((size_t)N_EDGES * 4);
    float* csr_w   = (float*)alloc((size_t)N_EDGES * 4);
    unsigned short* Xb  = (unsigned short*)alloc((size_t)N_NODES * 160 * 2);
    float* Y0  = (float*)alloc((size_t)N_NODES * 128 * 4);
    float* Y1  = (float*)alloc((size_t)N_NODES * 128 * 4);
    unsigned short* Y2b = (unsigned short*)alloc((size_t)N_NODES * 128 * 2);
    unsigned short* U   = (unsigned short*)alloc((size_t)N_NODES * 128 * 2);
    unsigned short* WT1 = (unsigned short*)alloc((size_t)384 * 160 * 2);
    unsigned short* WT2 = (unsigned short*)alloc((size_t)192 * 128 * 2);
    unsigned short* WT3 = (unsigned short*)alloc((size_t)96 * 64 * 2);

    const int BT = 256;
    hipMemsetAsync(deg, 0, N_NODES * 4, stream);
    hipMemsetAsync(cnt, 0, (size_t)SCAN_PAD * 4, stream);
    hipMemsetAsync(fill, 0, N_NODES * 4, stream);
    deg_count_kernel<<<(N_EDGES + BT - 1) / BT, BT, 0, stream>>>(src, dst, ea, deg, cnt, N_EDGES);
    dinv_kernel<<<(N_NODES + BT - 1) / BT, BT, 0, stream>>>(deg, dinv, N_NODES);
    scan_partial_kernel<<<SCAN_NB, BT, 0, stream>>>(cnt, partial);
    scan_offsets_kernel<<<1, 64, 0, stream>>>(partial, rowptr, SCAN_NB, N_NODES);
    scan_final_kernel<<<SCAN_NB, BT, 0, stream>>>(cnt, partial, rowptr, N_NODES);
    scatter_kernel<<<(N_EDGES + BT - 1) / BT, BT, 0, stream>>>(src, dst, ea, dinv, rowptr, fill,
                                                               csr_src, csr_w, N_EDGES);
    int n4 = N_NODES * 160 / 4;
    conv_bf16_kernel<<<(n4 + BT - 1) / BT, BT, 0, stream>>>(x, Xb, n4);
    wprep_kernel<<<(3 * 128 * 160 + BT - 1) / BT, BT, 0, stream>>>(W1, WT1, 160, 128);
    wprep_kernel<<<(3 * 64 * 128 + BT - 1) / BT, BT, 0, stream>>>(W2, WT2, 128, 64);
    wprep_kernel<<<(3 * 32 * 64 + BT - 1) / BT, BT, 0, stream>>>(W3, WT3, 64, 32);

    auto layer = [&](const unsigned short* WT, const float* bias, int FIN, int F) {
        dim3 ggrid((N_NODES + 127) / 128, (3 * F) / 32);
        cheb_gemm<<<ggrid, BT, 0, stream>>>(Xb, WT, Y0, Y1, Y2b, FIN, F, N_NODES);
        int gth = N_NODES * (F / 8);
        int ggr = (gth + BT - 1) / BT;
        gather_z_kernel<<<ggr, BT, 0, stream>>>(Y2b, csr_src, csr_w, rowptr, Y1, U, N_NODES, F);
        gather_v_kernel<<<ggr, BT, 0, stream>>>(U, csr_src, csr_w, rowptr, Y0, bias, Xb, N_NODES, F);
    };

    layer(WT1, b1, 160, 128);
    layer(WT2, b2, 128, 64);
    layer(WT3, b3, 64, 32);

    pool_kernel<<<NUM_G, BT, 0, stream>>>(Xb, batch, Wl, bl, out, N_NODES);
}

// Round 5
// 398.718 us; speedup vs baseline: 13.8749x; 1.0127x over previous
//
#include <hip/hip_runtime.h>

#define N_NODES 50000
#define N_EDGES 500000
#define NUM_G   128
#define SCAN_NB 49              // ceil(50000/1024)
#define SCAN_PAD (SCAN_NB * 1024)

typedef __attribute__((ext_vector_type(8))) short short8;
typedef __attribute__((ext_vector_type(4))) float f32x4;

__device__ __forceinline__ unsigned f2bf(float x) {
    unsigned u = __float_as_uint(x);
    return (u + 0x7FFFu + ((u >> 16) & 1u)) >> 16;   // RNE
}
__device__ __forceinline__ float bf2f(unsigned h) {
    return __uint_as_float(h << 16);
}

// ---------------- setup: degree + dst histogram ----------------
__global__ void deg_count_kernel(const int* __restrict__ src, const int* __restrict__ dst,
                                 const float* __restrict__ ea,
                                 float* __restrict__ deg, int* __restrict__ cnt, int E) {
    int e = blockIdx.x * blockDim.x + threadIdx.x;
    if (e < E) {
        atomicAdd(&deg[src[e]], ea[e]);
        atomicAdd(&cnt[dst[e]], 1);
    }
}

__global__ void dinv_kernel(const float* __restrict__ deg, float* __restrict__ dinv, int n) {
    int i = blockIdx.x * blockDim.x + threadIdx.x;
    if (i >= n) return;
    float d = deg[i];
    float r = 0.0f;
    if (d > 0.0f) {
        r = rsqrtf(d);
        r = r * (1.5f - 0.5f * d * r * r);
    }
    dinv[i] = r;
}

// ---------------- 3-phase scan ----------------
__global__ void scan_partial_kernel(const int* __restrict__ cnt, int* __restrict__ partial) {
    int b = blockIdx.x, t = threadIdx.x;
    int4 v = reinterpret_cast<const int4*>(cnt)[b * 256 + t];
    int s = v.x + v.y + v.z + v.w;
    __shared__ int red[256];
    red[t] = s;
    __syncthreads();
    for (int off = 128; off > 0; off >>= 1) {
        if (t < off) red[t] += red[t + off];
        __syncthreads();
    }
    if (t == 0) partial[b] = red[0];
}

__global__ void scan_offsets_kernel(int* __restrict__ partial, int* __restrict__ rowptr,
                                    int nb, int n) {
    int t = threadIdx.x;  // single wave of 64
    int orig = (t < nb) ? partial[t] : 0;
    int v = orig;
    for (int off = 1; off < 64; off <<= 1) {
        int u = __shfl_up(v, off, 64);
        if (t >= off) v += u;
    }
    if (t < nb) partial[t] = v - orig;
    if (t == nb - 1) rowptr[n] = v;
}

__global__ void scan_final_kernel(const int* __restrict__ cnt, const int* __restrict__ partial,
                                  int* __restrict__ rowptr, int n) {
    int b = blockIdx.x, t = threadIdx.x;
    int4 v = reinterpret_cast<const int4*>(cnt)[b * 256 + t];
    int s = v.x + v.y + v.z + v.w;
    __shared__ int red[256];
    red[t] = s;
    __syncthreads();
    for (int off = 1; off < 256; off <<= 1) {
        int u = (t >= off) ? red[t - off] : 0;
        __syncthreads();
        red[t] += u;
        __syncthreads();
    }
    int excl = partial[b] + ((t == 0) ? 0 : red[t - 1]);
    int i0 = b * 1024 + t * 4;
    if (i0 < n)     rowptr[i0]     = excl;
    if (i0 + 1 < n) rowptr[i0 + 1] = excl + v.x;
    if (i0 + 2 < n) rowptr[i0 + 2] = excl + v.x + v.y;
    if (i0 + 3 < n) rowptr[i0 + 3] = excl + v.x + v.y + v.z;
}

__global__ void scatter_kernel(const int* __restrict__ src, const int* __restrict__ dst,
                               const float* __restrict__ ea, const float* __restrict__ dinv,
                               const int* __restrict__ rowptr, int* __restrict__ fill,
                               int* __restrict__ csr_src, float* __restrict__ csr_w, int E) {
    int e = blockIdx.x * blockDim.x + threadIdx.x;
    if (e >= E) return;
    int s = src[e], d = dst[e];
    float wv = -dinv[s] * ea[e] * dinv[d];
    int pos = rowptr[d] + atomicAdd(&fill[d], 1);
    csr_src[pos] = s;
    csr_w[pos] = wv;
}

// ---------------- fp32 -> bf16 conversion ----------------
__global__ void conv_bf16_kernel(const float* __restrict__ x, unsigned short* __restrict__ o, int n4) {
    int t = blockIdx.x * blockDim.x + threadIdx.x;
    if (t >= n4) return;
    float4 v = reinterpret_cast<const float4*>(x)[t];
    ushort4 r;
    r.x = (unsigned short)f2bf(v.x);
    r.y = (unsigned short)f2bf(v.y);
    r.z = (unsigned short)f2bf(v.z);
    r.w = (unsigned short)f2bf(v.w);
    *reinterpret_cast<ushort4*>(o + (size_t)t * 4) = r;
}

// Build WcatT bf16: WT[n][k], n in [0,3F), k in [0,FIN)
__global__ void wprep_kernel(const float* __restrict__ W, unsigned short* __restrict__ WT,
                             int FIN, int F) {
    int t = blockIdx.x * blockDim.x + threadIdx.x;
    int total = 3 * F * FIN;
    if (t >= total) return;
    int n = t / FIN, k = t - n * FIN;
    int sel = n / F, c = n - sel * F;
    float v;
    if (sel == 0) v = W[(size_t)k * F + c] - W[(size_t)2 * FIN * F + (size_t)k * F + c];
    else          v = W[(size_t)sel * FIN * F + (size_t)k * F + c];
    WT[t] = (unsigned short)f2bf(v);
}

// ---------------- MFMA GEMM: [Y0|Y1|Y2] = Xb @ WcatT^T  (all outputs bf16) ------
// One block per 128-row M-tile. A staged in LDS once (full K), A-frags in regs,
// loop over all 3F/32 n-tiles restaging only the 32xFIN B tile (L2-resident).
// LDS row stride = FIN+8 shorts: 16B-aligned, dword-stride%32==4 -> 2-way max (free).
__launch_bounds__(256)
__global__ void cheb_gemm(const unsigned short* __restrict__ Xb, const unsigned short* __restrict__ WT,
                          unsigned short* __restrict__ Y0, unsigned short* __restrict__ Y1,
                          unsigned short* __restrict__ Y2,
                          int FIN, int F, int nrows) {
    __shared__ short As[128 * 168];   // max FIN=160 -> stride 168
    __shared__ short Bs[32 * 168];
    const int SA = FIN + 8;
    int tid = threadIdx.x;
    int lane = tid & 63, w = tid >> 6;
    int m0 = blockIdx.x * 128;
    int f8n = FIN >> 3;               // 16B spans per row

    // stage A: 128 rows x FIN, full K
    for (int span = tid; span < 128 * f8n; span += 256) {
        int r = span / f8n, c8 = (span - r * f8n) << 3;
        int row = m0 + r;
        uint4 v = make_uint4(0u, 0u, 0u, 0u);
        if (row < nrows)
            v = *reinterpret_cast<const uint4*>(Xb + (size_t)row * FIN + c8);
        *reinterpret_cast<uint4*>(&As[r * SA + c8]) = v;
    }
    __syncthreads();

    // hoist A fragments to registers: [ktile][m-subtile]
    int q8 = (lane >> 4) << 3;
    int mr = (lane & 15) + w * 32;
    short8 afr[5][2];
    int ktiles = FIN >> 5;
    for (int kt = 0; kt < ktiles; ++kt) {
        afr[kt][0] = *reinterpret_cast<const short8*>(&As[mr * SA + (kt << 5) + q8]);
        afr[kt][1] = *reinterpret_cast<const short8*>(&As[(mr + 16) * SA + (kt << 5) + q8]);
    }

    int colb = lane & 15;
    int rq = (lane >> 4) << 2;
    int ntiles = (3 * F) >> 5;
    for (int nt = 0; nt < ntiles; ++nt) {
        int n0 = nt << 5;
        __syncthreads();   // protect Bs from previous iteration's readers
        // stage B tile: 32 rows x FIN
        for (int span = tid; span < 32 * f8n; span += 256) {
            int r = span / f8n, c8 = (span - r * f8n) << 3;
            *reinterpret_cast<uint4*>(&Bs[r * SA + c8]) =
                *reinterpret_cast<const uint4*>(WT + (size_t)(n0 + r) * FIN + c8);
        }
        __syncthreads();

        f32x4 acc00 = {0.f, 0.f, 0.f, 0.f}, acc01 = acc00, acc10 = acc00, acc11 = acc00;
        for (int kt = 0; kt < ktiles; ++kt) {
            short8 b0 = *reinterpret_cast<const short8*>(&Bs[colb * SA + (kt << 5) + q8]);
            short8 b1 = *reinterpret_cast<const short8*>(&Bs[(colb + 16) * SA + (kt << 5) + q8]);
            acc00 = __builtin_amdgcn_mfma_f32_16x16x32_bf16(afr[kt][0], b0, acc00, 0, 0, 0);
            acc01 = __builtin_amdgcn_mfma_f32_16x16x32_bf16(afr[kt][0], b1, acc01, 0, 0, 0);
            acc10 = __builtin_amdgcn_mfma_f32_16x16x32_bf16(afr[kt][1], b0, acc10, 0, 0, 0);
            acc11 = __builtin_amdgcn_mfma_f32_16x16x32_bf16(afr[kt][1], b1, acc11, 0, 0, 0);
        }

        // epilogue: C/D layout col=lane&15, row=(lane>>4)*4+reg
        int sel = n0 / F;
        int lcb = n0 - sel * F;
        unsigned short* Ys = (sel == 0) ? Y0 : (sel == 1) ? Y1 : Y2;
        f32x4 accs[2][2] = {{acc00, acc01}, {acc10, acc11}};
        #pragma unroll
        for (int mt = 0; mt < 2; ++mt) {
            #pragma unroll
            for (int ns = 0; ns < 2; ++ns) {
                #pragma unroll
                for (int r = 0; r < 4; ++r) {
                    int row = m0 + w * 32 + mt * 16 + rq + r;
                    if (row >= nrows) continue;
                    Ys[(size_t)row * F + lcb + ns * 16 + colb] = (unsigned short)f2bf(accs[mt][ns][r]);
                }
            }
        }
    }
}

// ---------------- bf16 CSR gathers with fused epilogues ----------------
__device__ __forceinline__ void acc8(float* acc, uint4 p, float wv) {
    acc[0] += wv * bf2f(p.x & 0xFFFFu);
    acc[1] += wv * __uint_as_float(p.x & 0xFFFF0000u);
    acc[2] += wv * bf2f(p.y & 0xFFFFu);
    acc[3] += wv * __uint_as_float(p.y & 0xFFFF0000u);
    acc[4] += wv * bf2f(p.z & 0xFFFFu);
    acc[5] += wv * __uint_as_float(p.z & 0xFFFF0000u);
    acc[6] += wv * bf2f(p.w & 0xFFFFu);
    acc[7] += wv * __uint_as_float(p.w & 0xFFFF0000u);
}

__device__ __forceinline__ void expand8(uint4 p, float* o) {
    o[0] = bf2f(p.x & 0xFFFFu);
    o[1] = __uint_as_float(p.x & 0xFFFF0000u);
    o[2] = bf2f(p.y & 0xFFFFu);
    o[3] = __uint_as_float(p.y & 0xFFFF0000u);
    o[4] = bf2f(p.z & 0xFFFFu);
    o[5] = __uint_as_float(p.z & 0xFFFF0000u);
    o[6] = bf2f(p.w & 0xFFFFu);
    o[7] = __uint_as_float(p.w & 0xFFFF0000u);
}

// Z = P(Y2);  U = bf16(Y1 + 2Z)
__global__ void gather_z_kernel(const unsigned short* __restrict__ X, const int* __restrict__ csr_src,
                                const float* __restrict__ csr_w, const int* __restrict__ rowptr,
                                const unsigned short* __restrict__ Y1, unsigned short* __restrict__ U,
                                int n, int F) {
    int Fq8 = F >> 3;
    int t = blockIdx.x * blockDim.x + threadIdx.x;
    int d = t / Fq8;
    if (d >= n) return;
    int f8 = (t - d * Fq8) << 3;
    int beg = rowptr[d], end = rowptr[d + 1];
    float acc[8] = {0.f, 0.f, 0.f, 0.f, 0.f, 0.f, 0.f, 0.f};
    int i = beg;
    for (; i + 1 < end; i += 2) {
        int s0 = csr_src[i], s1 = csr_src[i + 1];
        float w0 = csr_w[i], w1 = csr_w[i + 1];
        uint4 p0 = *reinterpret_cast<const uint4*>(X + (size_t)s0 * F + f8);
        uint4 p1 = *reinterpret_cast<const uint4*>(X + (size_t)s1 * F + f8);
        acc8(acc, p0, w0);
        acc8(acc, p1, w1);
    }
    if (i < end) {
        uint4 p0 = *reinterpret_cast<const uint4*>(X + (size_t)csr_src[i] * F + f8);
        acc8(acc, p0, csr_w[i]);
    }
    float y[8];
    expand8(*reinterpret_cast<const uint4*>(Y1 + (size_t)d * F + f8), y);
    uint4 o;
    o.x = f2bf(y[0] + 2.f * acc[0]) | (f2bf(y[1] + 2.f * acc[1]) << 16);
    o.y = f2bf(y[2] + 2.f * acc[2]) | (f2bf(y[3] + 2.f * acc[3]) << 16);
    o.z = f2bf(y[4] + 2.f * acc[4]) | (f2bf(y[5] + 2.f * acc[5]) << 16);
    o.w = f2bf(y[6] + 2.f * acc[6]) | (f2bf(y[7] + 2.f * acc[7]) << 16);
    *reinterpret_cast<uint4*>(U + (size_t)d * F + f8) = o;
}

// V = P(U);  Xn = bf16(relu(Y0 + V + b))
__global__ void gather_v_kernel(const unsigned short* __restrict__ X, const int* __restrict__ csr_src,
                                const float* __restrict__ csr_w, const int* __restrict__ rowptr,
                                const unsigned short* __restrict__ Y0, const float* __restrict__ bias,
                                unsigned short* __restrict__ Xn, int n, int F) {
    int Fq8 = F >> 3;
    int t = blockIdx.x * blockDim.x + threadIdx.x;
    int d = t / Fq8;
    if (d >= n) return;
    int f8 = (t - d * Fq8) << 3;
    int beg = rowptr[d], end = rowptr[d + 1];
    float acc[8] = {0.f, 0.f, 0.f, 0.f, 0.f, 0.f, 0.f, 0.f};
    int i = beg;
    for (; i + 1 < end; i += 2) {
        int s0 = csr_src[i], s1 = csr_src[i + 1];
        float w0 = csr_w[i], w1 = csr_w[i + 1];
        uint4 p0 = *reinterpret_cast<const uint4*>(X + (size_t)s0 * F + f8);
        uint4 p1 = *reinterpret_cast<const uint4*>(X + (size_t)s1 * F + f8);
        acc8(acc, p0, w0);
        acc8(acc, p1, w1);
    }
    if (i < end) {
        uint4 p0 = *reinterpret_cast<const uint4*>(X + (size_t)csr_src[i] * F + f8);
        acc8(acc, p0, csr_w[i]);
    }
    float y[8];
    expand8(*reinterpret_cast<const uint4*>(Y0 + (size_t)d * F + f8), y);
    float4 ba = *reinterpret_cast<const float4*>(bias + f8);
    float4 bb = *reinterpret_cast<const float4*>(bias + f8 + 4);
    float v0 = fmaxf(y[0] + acc[0] + ba.x, 0.f);
    float v1 = fmaxf(y[1] + acc[1] + ba.y, 0.f);
    float v2 = fmaxf(y[2] + acc[2] + ba.z, 0.f);
    float v3 = fmaxf(y[3] + acc[3] + ba.w, 0.f);
    float v4 = fmaxf(y[4] + acc[4] + bb.x, 0.f);
    float v5 = fmaxf(y[5] + acc[5] + bb.y, 0.f);
    float v6 = fmaxf(y[6] + acc[6] + bb.z, 0.f);
    float v7 = fmaxf(y[7] + acc[7] + bb.w, 0.f);
    uint4 o;
    o.x = f2bf(v0) | (f2bf(v1) << 16);
    o.y = f2bf(v2) | (f2bf(v3) << 16);
    o.z = f2bf(v4) | (f2bf(v5) << 16);
    o.w = f2bf(v6) | (f2bf(v7) << 16);
    *reinterpret_cast<uint4*>(Xn + (size_t)d * F + f8) = o;
}

// ---------------- pooling + final linear ----------------
__device__ __forceinline__ int lower_bound_dev(const int* __restrict__ a, int n, int v) {
    int lo = 0, hi = n;
    while (lo < hi) {
        int mid = (lo + hi) >> 1;
        if (a[mid] < v) lo = mid + 1; else hi = mid;
    }
    return lo;
}

__global__ void pool_kernel(const unsigned short* __restrict__ H, const int* __restrict__ batch,
                            const float* __restrict__ Wl, const float* __restrict__ bl,
                            float* __restrict__ out, int n) {
    int g = blockIdx.x;
    int start = lower_bound_dev(batch, n, g);
    int end   = lower_bound_dev(batch, n, g + 1);
    int tid = threadIdx.x;
    int f = tid & 31;
    int sub = tid >> 5;
    float acc = 0.0f;
    for (int i = start + sub; i < end; i += 8)
        acc += bf2f((unsigned)H[(size_t)i * 32 + f]);
    __shared__ float red[256];
    red[tid] = acc;
    __syncthreads();
    if (tid < 128) red[tid] += red[tid + 128];
    __syncthreads();
    if (tid < 64) red[tid] += red[tid + 64];
    __syncthreads();
    if (tid < 32) red[tid] += red[tid + 32];
    __syncthreads();
    if (tid < 2) {
        int cnt = end - start;
        float inv = 1.0f / (float)(cnt > 0 ? cnt : 1);
        float o = bl[tid];
        for (int f2 = 0; f2 < 32; ++f2)
            o += red[f2] * inv * Wl[f2 * 2 + tid];
        out[g * 2 + tid] = o;
    }
}

extern "C" void kernel_launch(void* const* d_in, const int* in_sizes, int n_in,
                              void* d_out, int out_size, void* d_ws, size_t ws_size,
                              hipStream_t stream) {
    const float* x     = (const float*)d_in[0];
    const int*   ei    = (const int*)d_in[1];
    const float* ea    = (const float*)d_in[2];
    const int*   batch = (const int*)d_in[3];
    const float* W1 = (const float*)d_in[4];
    const float* b1 = (const float*)d_in[5];
    const float* W2 = (const float*)d_in[6];
    const float* b2 = (const float*)d_in[7];
    const float* W3 = (const float*)d_in[8];
    const float* b3 = (const float*)d_in[9];
    const float* Wl = (const float*)d_in[10];
    const float* bl = (const float*)d_in[11];
    float* out = (float*)d_out;
    char* ws = (char*)d_ws;

    const int* src = ei;
    const int* dst = ei + N_EDGES;

    size_t off = 0;
    auto alloc = [&](size_t bytes) { char* p = ws + off; off += (bytes + 255) & ~(size_t)255; return p; };
    float* deg     = (float*)alloc(N_NODES * 4);
    float* dinv    = (float*)alloc(N_NODES * 4);
    int*   cnt     = (int*)  alloc((size_t)SCAN_PAD * 4);
    int*   partial = (int*)  alloc(SCAN_NB * 4);
    int*   rowptr  = (int*)  alloc((N_NODES + 1) * 4);
    int*   fill    = (int*)  alloc(N_NODES * 4);
    int*   csr_src = (int*)  alloc((size_t)N_EDGES * 4);
    float* csr_w   = (float*)alloc((size_t)N_EDGES * 4);
    unsigned short* Xb  = (unsigned short*)alloc((size_t)N_NODES * 160 * 2);
    unsigned short* Y0  = (unsigned short*)alloc((size_t)N_NODES * 128 * 2);
    unsigned short* Y1  = (unsigned short*)alloc((size_t)N_NODES * 128 * 2);
    unsigned short* Y2  = (unsigned short*)alloc((size_t)N_NODES * 128 * 2);
    unsigned short* U   = (unsigned short*)alloc((size_t)N_NODES * 128 * 2);
    unsigned short* WT1 = (unsigned short*)alloc((size_t)384 * 160 * 2);
    unsigned short* WT2 = (unsigned short*)alloc((size_t)192 * 128 * 2);
    unsigned short* WT3 = (unsigned short*)alloc((size_t)96 * 64 * 2);

    const int BT = 256;
    hipMemsetAsync(deg, 0, N_NODES * 4, stream);
    hipMemsetAsync(cnt, 0, (size_t)SCAN_PAD * 4, stream);
    hipMemsetAsync(fill, 0, N_NODES * 4, stream);
    deg_count_kernel<<<(N_EDGES + BT - 1) / BT, BT, 0, stream>>>(src, dst, ea, deg, cnt, N_EDGES);
    dinv_kernel<<<(N_NODES + BT - 1) / BT, BT, 0, stream>>>(deg, dinv, N_NODES);
    scan_partial_kernel<<<SCAN_NB, BT, 0, stream>>>(cnt, partial);
    scan_offsets_kernel<<<1, 64, 0, stream>>>(partial, rowptr, SCAN_NB, N_NODES);
    scan_final_kernel<<<SCAN_NB, BT, 0, stream>>>(cnt, partial, rowptr, N_NODES);
    scatter_kernel<<<(N_EDGES + BT - 1) / BT, BT, 0, stream>>>(src, dst, ea, dinv, rowptr, fill,
                                                               csr_src, csr_w, N_EDGES);
    int n4 = N_NODES * 160 / 4;
    conv_bf16_kernel<<<(n4 + BT - 1) / BT, BT, 0, stream>>>(x, Xb, n4);
    wprep_kernel<<<(3 * 128 * 160 + BT - 1) / BT, BT, 0, stream>>>(W1, WT1, 160, 128);
    wprep_kernel<<<(3 * 64 * 128 + BT - 1) / BT, BT, 0, stream>>>(W2, WT2, 128, 64);
    wprep_kernel<<<(3 * 32 * 64 + BT - 1) / BT, BT, 0, stream>>>(W3, WT3, 64, 32);

    auto layer = [&](const unsigned short* WT, const float* bias, int FIN, int F) {
        int mgrid = (N_NODES + 127) / 128;
        cheb_gemm<<<mgrid, BT, 0, stream>>>(Xb, WT, Y0, Y1, Y2, FIN, F, N_NODES);
        int gth = N_NODES * (F / 8);
        int ggr = (gth + BT - 1) / BT;
        gather_z_kernel<<<ggr, BT, 0, stream>>>(Y2, csr_src, csr_w, rowptr, Y1, U, N_NODES, F);
        gather_v_kernel<<<ggr, BT, 0, stream>>>(U, csr_src, csr_w, rowptr, Y0, bias, Xb, N_NODES, F);
    };

    layer(WT1, b1, 160, 128);
    layer(WT2, b2, 128, 64);
    layer(WT3, b3, 64, 32);

    pool_kernel<<<NUM_G, BT, 0, stream>>>(Xb, batch, Wl, bl, out, N_NODES);
}

// Round 6
// 349.357 us; speedup vs baseline: 15.8353x; 1.1413x over previous
//
#include <hip/hip_runtime.h>

#define N_NODES 50000
#define N_EDGES 500000
#define NUM_G   128
#define SCAN_NB 49              // ceil(50000/1024)
#define SCAN_PAD (SCAN_NB * 1024)

typedef __attribute__((ext_vector_type(8))) short short8;
typedef __attribute__((ext_vector_type(4))) float f32x4;

__device__ __forceinline__ unsigned f2bf(float x) {
    unsigned u = __float_as_uint(x);
    return (u + 0x7FFFu + ((u >> 16) & 1u)) >> 16;   // RNE
}
__device__ __forceinline__ float bf2f(unsigned h) {
    return __uint_as_float(h << 16);
}

// ---------------- setup: degree + dst histogram ----------------
__global__ void deg_count_kernel(const int* __restrict__ src, const int* __restrict__ dst,
                                 const float* __restrict__ ea,
                                 float* __restrict__ deg, int* __restrict__ cnt, int E) {
    int e = blockIdx.x * blockDim.x + threadIdx.x;
    if (e < E) {
        atomicAdd(&deg[src[e]], ea[e]);
        atomicAdd(&cnt[dst[e]], 1);
    }
}

__global__ void dinv_kernel(const float* __restrict__ deg, float* __restrict__ dinv, int n) {
    int i = blockIdx.x * blockDim.x + threadIdx.x;
    if (i >= n) return;
    float d = deg[i];
    float r = 0.0f;
    if (d > 0.0f) {
        r = rsqrtf(d);
        r = r * (1.5f - 0.5f * d * r * r);
    }
    dinv[i] = r;
}

// ---------------- 3-phase scan ----------------
__global__ void scan_partial_kernel(const int* __restrict__ cnt, int* __restrict__ partial) {
    int b = blockIdx.x, t = threadIdx.x;
    int4 v = reinterpret_cast<const int4*>(cnt)[b * 256 + t];
    int s = v.x + v.y + v.z + v.w;
    __shared__ int red[256];
    red[t] = s;
    __syncthreads();
    for (int off = 128; off > 0; off >>= 1) {
        if (t < off) red[t] += red[t + off];
        __syncthreads();
    }
    if (t == 0) partial[b] = red[0];
}

__global__ void scan_offsets_kernel(int* __restrict__ partial, int* __restrict__ rowptr,
                                    int nb, int n) {
    int t = threadIdx.x;  // single wave of 64
    int orig = (t < nb) ? partial[t] : 0;
    int v = orig;
    for (int off = 1; off < 64; off <<= 1) {
        int u = __shfl_up(v, off, 64);
        if (t >= off) v += u;
    }
    if (t < nb) partial[t] = v - orig;
    if (t == nb - 1) rowptr[n] = v;
}

__global__ void scan_final_kernel(const int* __restrict__ cnt, const int* __restrict__ partial,
                                  int* __restrict__ rowptr, int n) {
    int b = blockIdx.x, t = threadIdx.x;
    int4 v = reinterpret_cast<const int4*>(cnt)[b * 256 + t];
    int s = v.x + v.y + v.z + v.w;
    __shared__ int red[256];
    red[t] = s;
    __syncthreads();
    for (int off = 1; off < 256; off <<= 1) {
        int u = (t >= off) ? red[t - off] : 0;
        __syncthreads();
        red[t] += u;
        __syncthreads();
    }
    int excl = partial[b] + ((t == 0) ? 0 : red[t - 1]);
    int i0 = b * 1024 + t * 4;
    if (i0 < n)     rowptr[i0]     = excl;
    if (i0 + 1 < n) rowptr[i0 + 1] = excl + v.x;
    if (i0 + 2 < n) rowptr[i0 + 2] = excl + v.x + v.y;
    if (i0 + 3 < n) rowptr[i0 + 3] = excl + v.x + v.y + v.z;
}

__global__ void scatter_kernel(const int* __restrict__ src, const int* __restrict__ dst,
                               const float* __restrict__ ea, const float* __restrict__ dinv,
                               const int* __restrict__ rowptr, int* __restrict__ fill,
                               int* __restrict__ csr_src, float* __restrict__ csr_w, int E) {
    int e = blockIdx.x * blockDim.x + threadIdx.x;
    if (e >= E) return;
    int s = src[e], d = dst[e];
    float wv = -dinv[s] * ea[e] * dinv[d];
    int pos = rowptr[d] + atomicAdd(&fill[d], 1);
    csr_src[pos] = s;
    csr_w[pos] = wv;
}

// ---------------- fp32 -> bf16 conversion ----------------
__global__ void conv_bf16_kernel(const float* __restrict__ x, unsigned short* __restrict__ o, int n4) {
    int t = blockIdx.x * blockDim.x + threadIdx.x;
    if (t >= n4) return;
    float4 v = reinterpret_cast<const float4*>(x)[t];
    ushort4 r;
    r.x = (unsigned short)f2bf(v.x);
    r.y = (unsigned short)f2bf(v.y);
    r.z = (unsigned short)f2bf(v.z);
    r.w = (unsigned short)f2bf(v.w);
    *reinterpret_cast<ushort4*>(o + (size_t)t * 4) = r;
}

// Build WcatT bf16: WT[n][k], n in [0,3F), k in [0,FIN)
__global__ void wprep_kernel(const float* __restrict__ W, unsigned short* __restrict__ WT,
                             int FIN, int F) {
    int t = blockIdx.x * blockDim.x + threadIdx.x;
    int total = 3 * F * FIN;
    if (t >= total) return;
    int n = t / FIN, k = t - n * FIN;
    int sel = n / F, c = n - sel * F;
    float v;
    if (sel == 0) v = W[(size_t)k * F + c] - W[(size_t)2 * FIN * F + (size_t)k * F + c];
    else          v = W[(size_t)sel * FIN * F + (size_t)k * F + c];
    WT[t] = (unsigned short)f2bf(v);
}

// ---------------- MFMA GEMM: [Y0|Y1|Y2] = Xb @ WcatT^T  (bf16 out) ----------------
// M-tile 64, grid (nrows/64, 3). Group g computes output matrix g (3F/3 = F cols).
// A fragments: direct global->reg (16 rows x 64B full lines per instruction).
// B tile in LDS with column-interleave perm: slot r holds WT col (r<16 ? 2r : 2(r-16)+1),
// so lane's (b0,b1) accs are adjacent cols -> ushort2 pack -> 64B-line stores.
template<int FIN, int F>
__launch_bounds__(256)
__global__ void cheb_gemm(const unsigned short* __restrict__ Xb, const unsigned short* __restrict__ WT,
                          unsigned short* __restrict__ Y0, unsigned short* __restrict__ Y1,
                          unsigned short* __restrict__ Y2,
                          int nrows) {
    constexpr int KT = FIN / 32;        // k-tiles
    constexpr int NT = F / 32;          // n-tiles per group (group = one output matrix)
    constexpr int SA = FIN + 8;         // LDS row stride (shorts): 16B-aligned, dword%32==4 -> 2-way (free)
    constexpr int F8 = FIN / 8;         // 16B spans per row
    __shared__ short Bs[32 * SA];

    int tid = threadIdx.x;
    int lane = tid & 63, w = tid >> 6;
    int m0 = blockIdx.x * 64;
    int g = blockIdx.y;                 // 0,1,2 -> Y0,Y1,Y2
    unsigned short* Ys = (g == 0) ? Y0 : (g == 1) ? Y1 : Y2;

    int colb = lane & 15;
    int q8 = (lane >> 4) << 3;
    int rq = (lane >> 4) << 2;
    int arow = m0 + w * 16 + colb;      // A row for this lane (m = lane&15)
    bool rok = arow < nrows;

    short8 afr[KT];
    #pragma unroll
    for (int kt = 0; kt < KT; ++kt) {
        short8 z = {0, 0, 0, 0, 0, 0, 0, 0};
        afr[kt] = rok ? *reinterpret_cast<const short8*>(Xb + (size_t)arow * FIN + (kt << 5) + q8) : z;
    }

    for (int nt = 0; nt < NT; ++nt) {
        int n0 = (g * NT + nt) << 5;    // global col-block in WT
        __syncthreads();                // protect Bs from previous iteration's readers
        for (int span = tid; span < 32 * F8; span += 256) {
            int r = span / F8, c8 = (span - r * F8) << 3;
            int pr = (r < 16) ? (r << 1) : (((r - 16) << 1) + 1);
            *reinterpret_cast<uint4*>(&Bs[r * SA + c8]) =
                *reinterpret_cast<const uint4*>(WT + (size_t)(n0 + pr) * FIN + c8);
        }
        __syncthreads();

        f32x4 acc0 = {0.f, 0.f, 0.f, 0.f}, acc1 = acc0;
        #pragma unroll
        for (int kt = 0; kt < KT; ++kt) {
            short8 b0 = *reinterpret_cast<const short8*>(&Bs[colb * SA + (kt << 5) + q8]);
            short8 b1 = *reinterpret_cast<const short8*>(&Bs[(colb + 16) * SA + (kt << 5) + q8]);
            acc0 = __builtin_amdgcn_mfma_f32_16x16x32_bf16(afr[kt], b0, acc0, 0, 0, 0);
            acc1 = __builtin_amdgcn_mfma_f32_16x16x32_bf16(afr[kt], b1, acc1, 0, 0, 0);
        }

        // C/D layout: col=lane&15 (perm slot -> actual cols 2c, 2c+1), row=(lane>>4)*4+reg
        int lc = (nt << 5) + (colb << 1);
        #pragma unroll
        for (int r = 0; r < 4; ++r) {
            int orow = m0 + w * 16 + rq + r;
            if (orow < nrows) {
                unsigned pack = f2bf(acc0[r]) | (f2bf(acc1[r]) << 16);
                *reinterpret_cast<unsigned*>(Ys + (size_t)orow * F + lc) = pack;
            }
        }
    }
}

// ---------------- bf16 CSR gathers with fused epilogues ----------------
__device__ __forceinline__ void acc8(float* acc, uint4 p, float wv) {
    acc[0] += wv * bf2f(p.x & 0xFFFFu);
    acc[1] += wv * __uint_as_float(p.x & 0xFFFF0000u);
    acc[2] += wv * bf2f(p.y & 0xFFFFu);
    acc[3] += wv * __uint_as_float(p.y & 0xFFFF0000u);
    acc[4] += wv * bf2f(p.z & 0xFFFFu);
    acc[5] += wv * __uint_as_float(p.z & 0xFFFF0000u);
    acc[6] += wv * bf2f(p.w & 0xFFFFu);
    acc[7] += wv * __uint_as_float(p.w & 0xFFFF0000u);
}

__device__ __forceinline__ void expand8(uint4 p, float* o) {
    o[0] = bf2f(p.x & 0xFFFFu);
    o[1] = __uint_as_float(p.x & 0xFFFF0000u);
    o[2] = bf2f(p.y & 0xFFFFu);
    o[3] = __uint_as_float(p.y & 0xFFFF0000u);
    o[4] = bf2f(p.z & 0xFFFFu);
    o[5] = __uint_as_float(p.z & 0xFFFF0000u);
    o[6] = bf2f(p.w & 0xFFFFu);
    o[7] = __uint_as_float(p.w & 0xFFFF0000u);
}

// Z = P(Y2);  U = bf16(Y1 + 2Z)
__global__ void gather_z_kernel(const unsigned short* __restrict__ X, const int* __restrict__ csr_src,
                                const float* __restrict__ csr_w, const int* __restrict__ rowptr,
                                const unsigned short* __restrict__ Y1, unsigned short* __restrict__ U,
                                int n, int F) {
    int Fq8 = F >> 3;
    int t = blockIdx.x * blockDim.x + threadIdx.x;
    int d = t / Fq8;
    if (d >= n) return;
    int f8 = (t - d * Fq8) << 3;
    int beg = rowptr[d], end = rowptr[d + 1];
    float acc[8] = {0.f, 0.f, 0.f, 0.f, 0.f, 0.f, 0.f, 0.f};
    int i = beg;
    for (; i + 1 < end; i += 2) {
        int s0 = csr_src[i], s1 = csr_src[i + 1];
        float w0 = csr_w[i], w1 = csr_w[i + 1];
        uint4 p0 = *reinterpret_cast<const uint4*>(X + (size_t)s0 * F + f8);
        uint4 p1 = *reinterpret_cast<const uint4*>(X + (size_t)s1 * F + f8);
        acc8(acc, p0, w0);
        acc8(acc, p1, w1);
    }
    if (i < end) {
        uint4 p0 = *reinterpret_cast<const uint4*>(X + (size_t)csr_src[i] * F + f8);
        acc8(acc, p0, csr_w[i]);
    }
    float y[8];
    expand8(*reinterpret_cast<const uint4*>(Y1 + (size_t)d * F + f8), y);
    uint4 o;
    o.x = f2bf(y[0] + 2.f * acc[0]) | (f2bf(y[1] + 2.f * acc[1]) << 16);
    o.y = f2bf(y[2] + 2.f * acc[2]) | (f2bf(y[3] + 2.f * acc[3]) << 16);
    o.z = f2bf(y[4] + 2.f * acc[4]) | (f2bf(y[5] + 2.f * acc[5]) << 16);
    o.w = f2bf(y[6] + 2.f * acc[6]) | (f2bf(y[7] + 2.f * acc[7]) << 16);
    *reinterpret_cast<uint4*>(U + (size_t)d * F + f8) = o;
}

// V = P(U);  Xn = bf16(relu(Y0 + V + b))
__global__ void gather_v_kernel(const unsigned short* __restrict__ X, const int* __restrict__ csr_src,
                                const float* __restrict__ csr_w, const int* __restrict__ rowptr,
                                const unsigned short* __restrict__ Y0, const float* __restrict__ bias,
                                unsigned short* __restrict__ Xn, int n, int F) {
    int Fq8 = F >> 3;
    int t = blockIdx.x * blockDim.x + threadIdx.x;
    int d = t / Fq8;
    if (d >= n) return;
    int f8 = (t - d * Fq8) << 3;
    int beg = rowptr[d], end = rowptr[d + 1];
    float acc[8] = {0.f, 0.f, 0.f, 0.f, 0.f, 0.f, 0.f, 0.f};
    int i = beg;
    for (; i + 1 < end; i += 2) {
        int s0 = csr_src[i], s1 = csr_src[i + 1];
        float w0 = csr_w[i], w1 = csr_w[i + 1];
        uint4 p0 = *reinterpret_cast<const uint4*>(X + (size_t)s0 * F + f8);
        uint4 p1 = *reinterpret_cast<const uint4*>(X + (size_t)s1 * F + f8);
        acc8(acc, p0, w0);
        acc8(acc, p1, w1);
    }
    if (i < end) {
        uint4 p0 = *reinterpret_cast<const uint4*>(X + (size_t)csr_src[i] * F + f8);
        acc8(acc, p0, csr_w[i]);
    }
    float y[8];
    expand8(*reinterpret_cast<const uint4*>(Y0 + (size_t)d * F + f8), y);
    float4 ba = *reinterpret_cast<const float4*>(bias + f8);
    float4 bb = *reinterpret_cast<const float4*>(bias + f8 + 4);
    float v0 = fmaxf(y[0] + acc[0] + ba.x, 0.f);
    float v1 = fmaxf(y[1] + acc[1] + ba.y, 0.f);
    float v2 = fmaxf(y[2] + acc[2] + ba.z, 0.f);
    float v3 = fmaxf(y[3] + acc[3] + ba.w, 0.f);
    float v4 = fmaxf(y[4] + acc[4] + bb.x, 0.f);
    float v5 = fmaxf(y[5] + acc[5] + bb.y, 0.f);
    float v6 = fmaxf(y[6] + acc[6] + bb.z, 0.f);
    float v7 = fmaxf(y[7] + acc[7] + bb.w, 0.f);
    uint4 o;
    o.x = f2bf(v0) | (f2bf(v1) << 16);
    o.y = f2bf(v2) | (f2bf(v3) << 16);
    o.z = f2bf(v4) | (f2bf(v5) << 16);
    o.w = f2bf(v6) | (f2bf(v7) << 16);
    *reinterpret_cast<uint4*>(Xn + (size_t)d * F + f8) = o;
}

// ---------------- pooling + final linear ----------------
__device__ __forceinline__ int lower_bound_dev(const int* __restrict__ a, int n, int v) {
    int lo = 0, hi = n;
    while (lo < hi) {
        int mid = (lo + hi) >> 1;
        if (a[mid] < v) lo = mid + 1; else hi = mid;
    }
    return lo;
}

__global__ void pool_kernel(const unsigned short* __restrict__ H, const int* __restrict__ batch,
                            const float* __restrict__ Wl, const float* __restrict__ bl,
                            float* __restrict__ out, int n) {
    int g = blockIdx.x;
    int start = lower_bound_dev(batch, n, g);
    int end   = lower_bound_dev(batch, n, g + 1);
    int tid = threadIdx.x;
    int f = tid & 31;
    int sub = tid >> 5;
    float acc = 0.0f;
    for (int i = start + sub; i < end; i += 8)
        acc += bf2f((unsigned)H[(size_t)i * 32 + f]);
    __shared__ float red[256];
    red[tid] = acc;
    __syncthreads();
    if (tid < 128) red[tid] += red[tid + 128];
    __syncthreads();
    if (tid < 64) red[tid] += red[tid + 64];
    __syncthreads();
    if (tid < 32) red[tid] += red[tid + 32];
    __syncthreads();
    if (tid < 2) {
        int cnt = end - start;
        float inv = 1.0f / (float)(cnt > 0 ? cnt : 1);
        float o = bl[tid];
        for (int f2 = 0; f2 < 32; ++f2)
            o += red[f2] * inv * Wl[f2 * 2 + tid];
        out[g * 2 + tid] = o;
    }
}

extern "C" void kernel_launch(void* const* d_in, const int* in_sizes, int n_in,
                              void* d_out, int out_size, void* d_ws, size_t ws_size,
                              hipStream_t stream) {
    const float* x     = (const float*)d_in[0];
    const int*   ei    = (const int*)d_in[1];
    const float* ea    = (const float*)d_in[2];
    const int*   batch = (const int*)d_in[3];
    const float* W1 = (const float*)d_in[4];
    const float* b1 = (const float*)d_in[5];
    const float* W2 = (const float*)d_in[6];
    const float* b2 = (const float*)d_in[7];
    const float* W3 = (const float*)d_in[8];
    const float* b3 = (const float*)d_in[9];
    const float* Wl = (const float*)d_in[10];
    const float* bl = (const float*)d_in[11];
    float* out = (float*)d_out;
    char* ws = (char*)d_ws;

    const int* src = ei;
    const int* dst = ei + N_EDGES;

    size_t off = 0;
    auto alloc = [&](size_t bytes) { char* p = ws + off; off += (bytes + 255) & ~(size_t)255; return p; };
    float* deg     = (float*)alloc(N_NODES * 4);
    float* dinv    = (float*)alloc(N_NODES * 4);
    int*   cnt     = (int*)  alloc((size_t)SCAN_PAD * 4);
    int*   partial = (int*)  alloc(SCAN_NB * 4);
    int*   rowptr  = (int*)  alloc((N_NODES + 1) * 4);
    int*   fill    = (int*)  alloc(N_NODES * 4);
    int*   csr_src = (int*)  alloc((size_t)N_EDGES * 4);
    float* csr_w   = (float*)alloc((size_t)N_EDGES * 4);
    unsigned short* Xb  = (unsigned short*)alloc((size_t)N_NODES * 160 * 2);
    unsigned short* Y0  = (unsigned short*)alloc((size_t)N_NODES * 128 * 2);
    unsigned short* Y1  = (unsigned short*)alloc((size_t)N_NODES * 128 * 2);
    unsigned short* Y2  = (unsigned short*)alloc((size_t)N_NODES * 128 * 2);
    unsigned short* U   = (unsigned short*)alloc((size_t)N_NODES * 128 * 2);
    unsigned short* WT1 = (unsigned short*)alloc((size_t)384 * 160 * 2);
    unsigned short* WT2 = (unsigned short*)alloc((size_t)192 * 128 * 2);
    unsigned short* WT3 = (unsigned short*)alloc((size_t)96 * 64 * 2);

    const int BT = 256;
    hipMemsetAsync(deg, 0, N_NODES * 4, stream);
    hipMemsetAsync(cnt, 0, (size_t)SCAN_PAD * 4, stream);
    hipMemsetAsync(fill, 0, N_NODES * 4, stream);
    deg_count_kernel<<<(N_EDGES + BT - 1) / BT, BT, 0, stream>>>(src, dst, ea, deg, cnt, N_EDGES);
    dinv_kernel<<<(N_NODES + BT - 1) / BT, BT, 0, stream>>>(deg, dinv, N_NODES);
    scan_partial_kernel<<<SCAN_NB, BT, 0, stream>>>(cnt, partial);
    scan_offsets_kernel<<<1, 64, 0, stream>>>(partial, rowptr, SCAN_NB, N_NODES);
    scan_final_kernel<<<SCAN_NB, BT, 0, stream>>>(cnt, partial, rowptr, N_NODES);
    scatter_kernel<<<(N_EDGES + BT - 1) / BT, BT, 0, stream>>>(src, dst, ea, dinv, rowptr, fill,
                                                               csr_src, csr_w, N_EDGES);
    int n4 = N_NODES * 160 / 4;
    conv_bf16_kernel<<<(n4 + BT - 1) / BT, BT, 0, stream>>>(x, Xb, n4);
    wprep_kernel<<<(3 * 128 * 160 + BT - 1) / BT, BT, 0, stream>>>(W1, WT1, 160, 128);
    wprep_kernel<<<(3 * 64 * 128 + BT - 1) / BT, BT, 0, stream>>>(W2, WT2, 128, 64);
    wprep_kernel<<<(3 * 32 * 64 + BT - 1) / BT, BT, 0, stream>>>(W3, WT3, 64, 32);

    dim3 ggrid((N_NODES + 63) / 64, 3);
    auto gathers = [&](const float* bias, int F) {
        int gth = N_NODES * (F / 8);
        int ggr = (gth + BT - 1) / BT;
        gather_z_kernel<<<ggr, BT, 0, stream>>>(Y2, csr_src, csr_w, rowptr, Y1, U, N_NODES, F);
        gather_v_kernel<<<ggr, BT, 0, stream>>>(U, csr_src, csr_w, rowptr, Y0, bias, Xb, N_NODES, F);
    };

    cheb_gemm<160, 128><<<ggrid, BT, 0, stream>>>(Xb, WT1, Y0, Y1, Y2, N_NODES);
    gathers(b1, 128);
    cheb_gemm<128, 64><<<ggrid, BT, 0, stream>>>(Xb, WT2, Y0, Y1, Y2, N_NODES);
    gathers(b2, 64);
    cheb_gemm<64, 32><<<ggrid, BT, 0, stream>>>(Xb, WT3, Y0, Y1, Y2, N_NODES);
    gathers(b3, 32);

    pool_kernel<<<NUM_G, BT, 0, stream>>>(Xb, batch, Wl, bl, out, N_NODES);
}